// Round 11
// baseline (417.582 us; speedup 1.0000x reference)
//
#include <hip/hip_runtime.h>

#define N 8192
#define D 256

typedef unsigned short u16;
typedef unsigned int u32;
typedef short bf16x8 __attribute__((ext_vector_type(8)));
typedef float f32x4 __attribute__((ext_vector_type(4)));

__device__ __forceinline__ u16 f2bf(float f) {
    u32 u = __float_as_uint(f);
    u += 0x7FFFu + ((u >> 16) & 1u);
    return (u16)(u >> 16);
}
__device__ __forceinline__ float bf2f(u16 v) {
    return __uint_as_float(((u32)v) << 16);
}

#define MFMA(a, b, c) __builtin_amdgcn_mfma_f32_16x16x32_bf16((a), (b), (c), 0, 0, 0)

// ---------------- LayerNorm + bf16 casts: one wave per row ----------------
__global__ __launch_bounds__(256) void k_prep_ln(const float* __restrict__ h,
    const float* __restrict__ x, const float* __restrict__ gamma,
    const float* __restrict__ beta, u16* __restrict__ hnb, u16* __restrict__ xb)
{
    int lane = threadIdx.x & 63;
    int row = blockIdx.x * 4 + (threadIdx.x >> 6);
    const float4 hv = ((const float4*)(h + (size_t)row * D))[lane];
    float s = hv.x + hv.y + hv.z + hv.w;
    float s2 = hv.x * hv.x + hv.y * hv.y + hv.z * hv.z + hv.w * hv.w;
#pragma unroll
    for (int m = 1; m < 64; m <<= 1) { s += __shfl_xor(s, m); s2 += __shfl_xor(s2, m); }
    float mu = s * (1.0f / D);
    float var = s2 * (1.0f / D) - mu * mu;
    float rstd = rsqrtf(var + 1e-5f);
    const float4 gv = ((const float4*)gamma)[lane];
    const float4 bv = ((const float4*)beta)[lane];
    ushort4 o;
    o.x = f2bf((hv.x - mu) * rstd * gv.x + bv.x);
    o.y = f2bf((hv.y - mu) * rstd * gv.y + bv.y);
    o.z = f2bf((hv.z - mu) * rstd * gv.z + bv.z);
    o.w = f2bf((hv.w - mu) * rstd * gv.w + bv.w);
    ((ushort4*)(hnb + (size_t)row * D))[lane] = o;
    const float4 xv = ((const float4*)(x + (size_t)row * D))[lane];
    ushort4 xo;
    xo.x = f2bf(xv.x); xo.y = f2bf(xv.y); xo.z = f2bf(xv.z); xo.w = f2bf(xv.w);
    ((ushort4*)(xb + (size_t)row * D))[lane] = xo;
}

// ---------------- 256x256 f32 weight -> bf16 transpose ----------------
__global__ void k_wT(const float* __restrict__ Wk, const float* __restrict__ Wq,
                     const float* __restrict__ Wv, u16* __restrict__ wkT,
                     u16* __restrict__ wqT, u16* __restrict__ wvT)
{
    const float* src = blockIdx.y == 0 ? Wk : (blockIdx.y == 1 ? Wq : Wv);
    u16* dst = blockIdx.y == 0 ? wkT : (blockIdx.y == 1 ? wqT : wvT);
    int c = blockIdx.x, r = threadIdx.x;
    dst[c * D + r] = f2bf(src[r * D + c]);
}

// ---------------- [N][D] bf16 -> [D][N] bf16 transpose (LDS tiles) ----------------
__global__ __launch_bounds__(256) void k_transpose(const u16* __restrict__ s0,
    u16* __restrict__ d0, const u16* __restrict__ s1, u16* __restrict__ d1)
{
    const u16* src = blockIdx.y ? s1 : s0;
    u16* dst = blockIdx.y ? d1 : d0;
    int jb = (blockIdx.x & 127) * 64;
    int cb = (blockIdx.x >> 7) * 64;
    __shared__ u16 tile[64][72];
    int t = threadIdx.x;
#pragma unroll
    for (int i = 0; i < 2; ++i) {
        int id = t + i * 256;
        int r = id >> 3, ch = id & 7;
        uint4 v = *(const uint4*)(src + (size_t)(jb + r) * D + cb + ch * 8);
        *(uint4*)(&tile[r][ch * 8]) = v;
    }
    __syncthreads();
#pragma unroll
    for (int i = 0; i < 2; ++i) {
        int id = t + i * 256;
        int c = id >> 3, rch = id & 7;
        u16 vals[8] __attribute__((aligned(16)));
#pragma unroll
        for (int e = 0; e < 8; ++e) vals[e] = tile[rch * 8 + e][c];
        *(uint4*)(dst + (size_t)(cb + c) * N + jb + rch * 8) = *(const uint4*)vals;
    }
}

// ---------------- fused k&q projection: 16 rows/block, grid 512 ----------------
__global__ __launch_bounds__(256, 4) void k_proj_kq(const u16* __restrict__ A,
    const u16* __restrict__ wkT, const u16* __restrict__ wqT,
    u16* __restrict__ kb, u16* __restrict__ qb)
{
    int w = threadIdx.x >> 6;
    int lane = threadIdx.x & 63;
    int l16 = lane & 15, lhi = lane >> 4;
    int rows = blockIdx.x * 16;
    const u16* BT = (w >> 1) ? wqT : wkT;
    u16* out = (w >> 1) ? qb : kb;
    int colbase = (w & 1) * 128;
    const f32x4 z4 = {0.f, 0.f, 0.f, 0.f};
    f32x4 acc[8] = {z4, z4, z4, z4, z4, z4, z4, z4};
#pragma unroll
    for (int ks = 0; ks < 8; ++ks) {
        bf16x8 a = *(const bf16x8*)(A + (size_t)(rows + l16) * D + ks * 32 + lhi * 8);
#pragma unroll
        for (int cf = 0; cf < 8; ++cf) {
            bf16x8 b = *(const bf16x8*)(BT + (size_t)(colbase + cf * 16 + l16) * D + ks * 32 + lhi * 8);
            acc[cf] = MFMA(a, b, acc[cf]);
        }
    }
#pragma unroll
    for (int cf = 0; cf < 8; ++cf)
#pragma unroll
        for (int jj = 0; jj < 4; ++jj)
            out[(size_t)(rows + lhi * 4 + jj) * D + colbase + cf * 16 + l16] = f2bf(acc[cf][jj]);
}

// ---------------- small NT k-split: part[(ks*2+side)][i][j] = sum_{n in slice} P[i][n]Q[j][n] ----------------
__global__ __launch_bounds__(256) void k_small_nt(const u16* __restrict__ hnT,
    const u16* __restrict__ xT, float* __restrict__ part)
{
    const u16* P = blockIdx.y ? hnT : xT;
    const u16* Q = xT;
    int w = threadIdx.x >> 6;
    int lane = threadIdx.x & 63;
    int l16 = lane & 15, lhi = lane >> 4;
    int arow = blockIdx.x * 16;
    int bcol = w * 64;
    int n0b = blockIdx.z * 1024;
    const f32x4 z4 = {0.f, 0.f, 0.f, 0.f};
    f32x4 acc[4] = {z4, z4, z4, z4};
    for (int n0 = n0b; n0 < n0b + 1024; n0 += 32) {
        bf16x8 a = *(const bf16x8*)(P + (size_t)(arow + l16) * N + n0 + lhi * 8);
#pragma unroll
        for (int cf = 0; cf < 4; ++cf) {
            bf16x8 b = *(const bf16x8*)(Q + (size_t)(bcol + cf * 16 + l16) * N + n0 + lhi * 8);
            acc[cf] = MFMA(a, b, acc[cf]);
        }
    }
    float* dst = part + ((size_t)blockIdx.z * 2 + blockIdx.y) * 65536;
#pragma unroll
    for (int cf = 0; cf < 4; ++cf)
#pragma unroll
        for (int jj = 0; jj < 4; ++jj)
            dst[(size_t)(arow + lhi * 4 + jj) * D + bcol + cf * 16 + l16] = acc[cf][jj];
}

// ---------------- sum 8 k-slices + cast to bf16 ----------------
__global__ __launch_bounds__(256) void k_cast(const float* __restrict__ part,
    u16* __restrict__ Mb, u16* __restrict__ XHT)
{
    int t = blockIdx.x * 256 + threadIdx.x;   // 0..131071
    int side = t >> 16, idx = t & 65535;
    float s = 0.f;
#pragma unroll
    for (int ks = 0; ks < 8; ++ks) s += part[((size_t)ks * 2 + side) * 65536 + idx];
    (side ? XHT : Mb)[idx] = f2bf(s);
}

// ---------------- [N,256]@[256,256] 16-row GEMM; EPI 0: bf16 out, 1: elu+res f32 ----------------
template <int EPI>
__global__ __launch_bounds__(256, 4) void k_gemm16(const u16* __restrict__ A,
    const u16* __restrict__ BT, u16* __restrict__ outb,
    const float* __restrict__ res, float* __restrict__ outf)
{
    int w = threadIdx.x >> 6;
    int lane = threadIdx.x & 63;
    int l16 = lane & 15, lhi = lane >> 4;
    int rows = blockIdx.x * 16;
    int cols = w * 64;
    const f32x4 z4 = {0.f, 0.f, 0.f, 0.f};
    f32x4 acc[4] = {z4, z4, z4, z4};
#pragma unroll
    for (int ks = 0; ks < 8; ++ks) {
        bf16x8 a = *(const bf16x8*)(A + (size_t)(rows + l16) * D + ks * 32 + lhi * 8);
#pragma unroll
        for (int cf = 0; cf < 4; ++cf) {
            bf16x8 b = *(const bf16x8*)(BT + (size_t)(cols + cf * 16 + l16) * D + ks * 32 + lhi * 8);
            acc[cf] = MFMA(a, b, acc[cf]);
        }
    }
#pragma unroll
    for (int cf = 0; cf < 4; ++cf)
#pragma unroll
        for (int jj = 0; jj < 4; ++jj) {
            int r = rows + lhi * 4 + jj;
            int c = cols + cf * 16 + l16;
            float v = acc[cf][jj];
            if (EPI == 0) {
                outb[(size_t)r * D + c] = f2bf(v);
            } else {
                float z = v > 0.f ? v : expm1f(v);
                outf[(size_t)r * D + c] = z + res[(size_t)r * D + c];
            }
        }
}

// ---------------- fused S pass v11: v10 pipeline + conflict-free P stride 256 ----------------
// grid 512: xcd = wgid&7, js = xcd>>1 (j-slice 2048), rb = (wgid>>3)*2+(xcd&1), 64 rows.
// j-tile 128, 16 iters. Iter it: S[it] -> P[it&1], then PV[it-1] from P[(it-1)&1].
// ONE lgkm-only barrier per iter. P row stride 256B (== 0 mod 128B): XOR slot swizzle
// gives 16 distinct slots per 16-lane read group -> 2 lanes/bank = conflict-free.
__global__ __launch_bounds__(512, 4) void k_fused(const u16* __restrict__ kb,
    const u16* __restrict__ qb, const u16* __restrict__ hnT,
    const u16* __restrict__ xT, u16* __restrict__ accP, float* __restrict__ lpart)
{
    __shared__ u16 AK[64 * 256];      // 32KB: K rows, XOR slot swizzle
    __shared__ u16 P[2][64 * 128];    // 2 x 16KB: P tiles, row stride 256B, XOR slot swizzle
    const int tid = threadIdx.x;
    const int w = tid >> 6;
    const int lane = tid & 63;
    const int l16 = lane & 15, lhi = lane >> 4;
    const int wgid = blockIdx.x;
    const int xcd = wgid & 7;
    const int js = xcd >> 1;
    const int rb = ((wgid >> 3) << 1) | (xcd & 1);
    const int R0 = rb * 64;
    const int jbase = js * 2048;

    // ---- stage AK: physical slot = (s&16) | ((s&15) ^ (r&15)) ----
    {
        int r = tid >> 3, sb = (tid & 7) * 4;
        const u16* src = kb + (size_t)(R0 + r) * D + sb * 8;
#pragma unroll
        for (int i = 0; i < 4; ++i) {
            bf16x8 v = *(const bf16x8*)(src + i * 8);
            int s = sb + i;
            int slotp = (s & 16) | ((s & 15) ^ (r & 15));
            *(bf16x8*)(AK + r * 256 + slotp * 8) = v;
        }
    }

    // phase-1 role: rg = 32-row half (0..1), jf = 32-j chunk (0..3)
    const int rg = w & 1;
    const int jf = w >> 1;
    // phase-2 role: t2 = target (0=hn,1=x), ch = 64-col chunk (0..3)
    const int t2 = w >> 2;
    const int ch = w & 3;
    const u16* T = t2 ? xT : hnT;
    const u16* Tb0 = T + (size_t)(ch * 64 + 0 * 16 + l16) * N + lhi * 8;
    const u16* Tb1 = T + (size_t)(ch * 64 + 1 * 16 + l16) * N + lhi * 8;
    const u16* Tb2 = T + (size_t)(ch * 64 + 2 * 16 + l16) * N + lhi * 8;
    const u16* Tb3 = T + (size_t)(ch * 64 + 3 * 16 + l16) * N + lhi * 8;

    const f32x4 z4 = {0.f, 0.f, 0.f, 0.f};
    f32x4 acc[16];
#pragma unroll
    for (int i = 0; i < 16; ++i) acc[i] = z4;
    f32x4 red2[2] = {z4, z4};          // row-sum partials: red2[rf][jj]
    bf16x8 tp0[4], tp1[4];

    // S body: compute 64x128 S tile for iteration `it` into P[it&1]
    auto S_body = [&](int it) {
        const int jc = jbase + it * 128 + jf * 32;
        u16* PW = &P[it & 1][0];
        f32x4 cs00 = z4, cs01 = z4, cs10 = z4, cs11 = z4;
#pragma unroll
        for (int ks = 0; ks < 8; ++ks) {
            int r0 = rg * 32 + l16;
            int r1 = r0 + 16;
            int sq = ks * 4 + lhi;
            int slx = (sq & 16) | ((sq & 15) ^ l16);
            bf16x8 a0 = *(const bf16x8*)(AK + r0 * 256 + slx * 8);
            bf16x8 a1 = *(const bf16x8*)(AK + r1 * 256 + slx * 8);
            const u16* Bq = qb + (size_t)(jc + l16) * D + ks * 32 + lhi * 8;
            bf16x8 b0 = *(const bf16x8*)(Bq);
            bf16x8 b1 = *(const bf16x8*)(Bq + 16 * D);
            cs00 = MFMA(a0, b0, cs00);
            cs01 = MFMA(a0, b1, cs01);
            cs10 = MFMA(a1, b0, cs10);
            cs11 = MFMA(a1, b1, cs11);
        }
#pragma unroll
        for (int rf = 0; rf < 2; ++rf)
#pragma unroll
            for (int cfr = 0; cfr < 2; ++cfr) {
                f32x4 s4 = rf ? (cfr ? cs11 : cs10) : (cfr ? cs01 : cs00);
#pragma unroll
                for (int jj = 0; jj < 4; ++jj) {
                    int row = rg * 32 + rf * 16 + lhi * 4 + jj;
                    int col = jf * 32 + cfr * 16 + l16;     // 0..127
                    float pv = __expf(s4[jj] * 0.0625f);
                    red2[rf][jj] += pv;
                    int slot = (col >> 3) ^ (row & 15);     // 0..15
                    *(u16*)((char*)PW + row * 256 + slot * 16 + (col & 7) * 2) = f2bf(pv);
                }
            }
    };

    __syncthreads();           // AK visible
    S_body(0);                 // prologue: fill P[0]

    for (int it = 1; it <= 16; ++it) {
        // one barrier per iter (lgkm-only; vmem loads stay in flight)
        asm volatile("s_waitcnt lgkmcnt(0)\n\ts_barrier" ::: "memory");
        if (it < 16) S_body(it);

        const int jbp = jbase + (it - 1) * 128;
        const char* Pb = (const char*)&P[(it - 1) & 1][0];
        // T prefetch for kf=0,1
        tp0[0] = *(const bf16x8*)(Tb0 + jbp); tp0[1] = *(const bf16x8*)(Tb1 + jbp);
        tp0[2] = *(const bf16x8*)(Tb2 + jbp); tp0[3] = *(const bf16x8*)(Tb3 + jbp);
        tp1[0] = *(const bf16x8*)(Tb0 + jbp + 32); tp1[1] = *(const bf16x8*)(Tb1 + jbp + 32);
        tp1[2] = *(const bf16x8*)(Tb2 + jbp + 32); tp1[3] = *(const bf16x8*)(Tb3 + jbp + 32);

        __builtin_amdgcn_s_setprio(1);
#define PV_STEP(KF, TP)                                                             \
        {                                                                           \
            bf16x8 pa0 = *(const bf16x8*)(Pb + (0 * 16 + l16) * 256 + ((((KF) * 4 + lhi) ^ l16) << 4)); \
            bf16x8 pa1 = *(const bf16x8*)(Pb + (1 * 16 + l16) * 256 + ((((KF) * 4 + lhi) ^ l16) << 4)); \
            bf16x8 pa2 = *(const bf16x8*)(Pb + (2 * 16 + l16) * 256 + ((((KF) * 4 + lhi) ^ l16) << 4)); \
            bf16x8 pa3 = *(const bf16x8*)(Pb + (3 * 16 + l16) * 256 + ((((KF) * 4 + lhi) ^ l16) << 4)); \
            acc[0]  = MFMA(pa0, TP[0], acc[0]);  acc[1]  = MFMA(pa0, TP[1], acc[1]);  \
            acc[2]  = MFMA(pa0, TP[2], acc[2]);  acc[3]  = MFMA(pa0, TP[3], acc[3]);  \
            acc[4]  = MFMA(pa1, TP[0], acc[4]);  acc[5]  = MFMA(pa1, TP[1], acc[5]);  \
            acc[6]  = MFMA(pa1, TP[2], acc[6]);  acc[7]  = MFMA(pa1, TP[3], acc[7]);  \
            acc[8]  = MFMA(pa2, TP[0], acc[8]);  acc[9]  = MFMA(pa2, TP[1], acc[9]);  \
            acc[10] = MFMA(pa2, TP[2], acc[10]); acc[11] = MFMA(pa2, TP[3], acc[11]); \
            acc[12] = MFMA(pa3, TP[0], acc[12]); acc[13] = MFMA(pa3, TP[1], acc[13]); \
            acc[14] = MFMA(pa3, TP[2], acc[14]); acc[15] = MFMA(pa3, TP[3], acc[15]); \
            if ((KF) + 2 < 4) {                                                     \
                TP[0] = *(const bf16x8*)(Tb0 + jbp + ((KF) + 2) * 32);              \
                TP[1] = *(const bf16x8*)(Tb1 + jbp + ((KF) + 2) * 32);              \
                TP[2] = *(const bf16x8*)(Tb2 + jbp + ((KF) + 2) * 32);              \
                TP[3] = *(const bf16x8*)(Tb3 + jbp + ((KF) + 2) * 32);              \
            }                                                                       \
        }
        PV_STEP(0, tp0)
        PV_STEP(1, tp1)
        PV_STEP(2, tp0)
        PV_STEP(3, tp1)
#undef PV_STEP
        __builtin_amdgcn_s_setprio(0);
    }

    // ---- coalesced nontemporal partial store: wave-private [64 v][64 lane] bf16 ----
    {
        u16* base = accP + ((((size_t)js * 128 + rb) * 8 + w) * 64) * 64 + lane;
#pragma unroll
        for (int rf = 0; rf < 4; ++rf)
#pragma unroll
            for (int cf = 0; cf < 4; ++cf)
#pragma unroll
                for (int jj = 0; jj < 4; ++jj) {
                    int v = (rf * 4 + cf) * 4 + jj;
                    __builtin_nontemporal_store(f2bf(acc[rf * 4 + cf][jj]), base + (size_t)v * 64);
                }
    }
    // ---- softmax denominator partials ----
#pragma unroll
    for (int rf = 0; rf < 2; ++rf)
#pragma unroll
        for (int m = 1; m < 16; m <<= 1) {
            red2[rf][0] += __shfl_xor(red2[rf][0], m);
            red2[rf][1] += __shfl_xor(red2[rf][1], m);
            red2[rf][2] += __shfl_xor(red2[rf][2], m);
            red2[rf][3] += __shfl_xor(red2[rf][3], m);
        }
    if (l16 == 0)
#pragma unroll
        for (int rf = 0; rf < 2; ++rf)
#pragma unroll
            for (int jj = 0; jj < 4; ++jj)
                atomicAdd(lpart + R0 + rg * 32 + rf * 16 + lhi * 4 + jj, red2[rf][jj]);
}

// ---------------- per-row stats: l, gn = sqrt(x.(xM)), mixing -> 4 scalars ----------------
__global__ __launch_bounds__(256) void k_stats(const float* __restrict__ lpart,
    const u16* __restrict__ Ux, const u16* __restrict__ xb,
    const float* __restrict__ mixing, float* __restrict__ stats)
{
    int lane = threadIdx.x & 63;
    int row = blockIdx.x * 4 + (threadIdx.x >> 6);
    float sg = 0.f;
    {
        ushort4 yv = ((const ushort4*)(Ux + (size_t)row * D))[lane];
        ushort4 xv = ((const ushort4*)(xb + (size_t)row * D))[lane];
        sg += bf2f(yv.x) * bf2f(xv.x);
        sg += bf2f(yv.y) * bf2f(xv.y);
        sg += bf2f(yv.z) * bf2f(xv.z);
        sg += bf2f(yv.w) * bf2f(xv.w);
    }
#pragma unroll
    for (int m = 1; m < 64; m <<= 1) sg += __shfl_xor(sg, m);
    if (lane == 0) {
        float inv_l = 1.0f / lpart[row];
        float inv_g = 1.0f / fmaxf(sqrtf(fmaxf(sg, 0.f)), 1e-12f);
        float e00 = __expf(mixing[0]), e10 = __expf(mixing[2]);
        float c00 = e00 / (e00 + e10), c10 = e10 / (e00 + e10);
        float e01 = __expf(mixing[1]), e11 = __expf(mixing[3]);
        float c01 = e01 / (e01 + e11), c11 = e11 / (e01 + e11);
        float4 stv = { c00 * inv_l, c10 * inv_g, c01 * inv_l, c11 * inv_g };
        ((float4*)stats)[row] = stv;
    }
}

// ---------------- combine: 4 wave-layout slices + rank-256 terms -> hmixb & x_new ----------------
__global__ __launch_bounds__(256) void k_combine(const u16* __restrict__ accP,
    const float* __restrict__ stats, const u16* __restrict__ Uh,
    const u16* __restrict__ Ux, const float* __restrict__ x0,
    u16* __restrict__ hmixb, float* __restrict__ outx)
{
    int t = blockIdx.x * 256 + threadIdx.x;
    int r = t >> 7;
    int q = t & 127;
    int rb = r >> 6, rr = r & 63;
    int t2 = q >> 6;
    int cc = (q & 63) * 4;                 // col within 256 of this target
    int wv = t2 * 4 + (cc >> 6);
    int rf = rr >> 4, lhi = (rr >> 2) & 3, jj = rr & 3;
    int cf = (cc >> 4) & 3, l16 = cc & 15;
    int v = (rf * 4 + cf) * 4 + jj;
    int lane = lhi * 16 + l16;
    float v0 = 0.f, v1 = 0.f, v2 = 0.f, v3 = 0.f;
#pragma unroll
    for (int s = 0; s < 4; ++s) {
        const u16* bp = accP + ((((size_t)s * 128 + rb) * 8 + wv) * 64 + v) * 64 + lane;
        ushort4 a = *(const ushort4*)bp;
        v0 += bf2f(a.x); v1 += bf2f(a.y); v2 += bf2f(a.z); v3 += bf2f(a.w);
    }
    float4 st = ((const float4*)stats)[r];
    if (t2 == 0) {
        int c = cc;
        ushort4 u = *(const ushort4*)(Uh + (size_t)r * D + c);
        ushort4 o;
        o.x = f2bf(st.x * v0 + st.y * bf2f(u.x));
        o.y = f2bf(st.x * v1 + st.y * bf2f(u.y));
        o.z = f2bf(st.x * v2 + st.y * bf2f(u.z));
        o.w = f2bf(st.x * v3 + st.y * bf2f(u.w));
        *(ushort4*)(hmixb + (size_t)r * D + c) = o;
    } else {
        int c = cc;
        ushort4 u = *(const ushort4*)(Ux + (size_t)r * D + c);
        float4 xv = *(const float4*)(x0 + (size_t)r * D + c);
        float4 o;
        o.x = st.z * v0 + st.w * bf2f(u.x) + xv.x;
        o.y = st.z * v1 + st.w * bf2f(u.y) + xv.y;
        o.z = st.z * v2 + st.w * bf2f(u.z) + xv.z;
        o.w = st.z * v3 + st.w * bf2f(u.w) + xv.w;
        *(float4*)(outx + (size_t)r * D + c) = o;
    }
}

extern "C" void kernel_launch(void* const* d_in, const int* in_sizes, int n_in,
                              void* d_out, int out_size, void* d_ws, size_t ws_size,
                              hipStream_t stream)
{
    const float* h = (const float*)d_in[0];
    const float* x = (const float*)d_in[1];
    const float* Wk = (const float*)d_in[2];
    const float* Wq = (const float*)d_in[3];
    const float* Wv = (const float*)d_in[4];
    const float* gamma = (const float*)d_in[5];
    const float* beta = (const float*)d_in[6];
    const float* mixing = (const float*)d_in[7];

    char* p = (char*)d_ws;
    const size_t ND2 = (size_t)N * D * 2;
    u16* hnb = (u16*)p; p += ND2;   // reused as Uh after k_proj_kq
    u16* xb = (u16*)p; p += ND2;
    u16* kb = (u16*)p; p += ND2;    // reused as hmixb after k_fused
    u16* qb = (u16*)p; p += ND2;
    u16* hnT = (u16*)p; p += ND2;
    u16* xT = (u16*)p; p += ND2;
    u16* Ux = (u16*)p; p += ND2;
    u16* wkT = (u16*)p; p += (size_t)D * D * 2;
    u16* wqT = (u16*)p; p += (size_t)D * D * 2;
    u16* wvT = (u16*)p; p += (size_t)D * D * 2;
    u16* Mb = (u16*)p; p += (size_t)D * D * 2;
    u16* XHT = (u16*)p; p += (size_t)D * D * 2;
    u16* accP = (u16*)p; p += (size_t)4 * N * 512 * 2;   // 32 MB bf16 wave-layout partials
    float* ntpart = (float*)accP;                        // overlay: used before accP
    float* lpart = (float*)p; p += (size_t)N * 4;
    float* stats = (float*)p; p += (size_t)N * 4 * 4;
    u16* Uh = hnb;      // overlay (hnb dead after k_proj_kq)
    u16* hmixb = kb;    // overlay (kb dead after k_fused)
    // total ~= 61 MB

    float* outh = (float*)d_out;
    float* outx = outh + (size_t)N * D;

    hipMemsetAsync(lpart, 0, (size_t)N * 4, stream);
    k_prep_ln<<<N / 4, 256, 0, stream>>>(h, x, gamma, beta, hnb, xb);
    k_wT<<<dim3(256, 3), 256, 0, stream>>>(Wk, Wq, Wv, wkT, wqT, wvT);
    k_transpose<<<dim3(512, 2), 256, 0, stream>>>(hnb, hnT, xb, xT);
    k_proj_kq<<<512, 256, 0, stream>>>(hnb, wkT, wqT, kb, qb);
    k_small_nt<<<dim3(16, 2, 8), 256, 0, stream>>>(hnT, xT, ntpart);
    k_cast<<<512, 256, 0, stream>>>(ntpart, Mb, XHT);
    k_gemm16<0><<<512, 256, 0, stream>>>(xb, Mb, Ux, nullptr, nullptr);
    k_gemm16<0><<<512, 256, 0, stream>>>(xb, XHT, Uh, nullptr, nullptr);
    k_fused<<<512, 512, 0, stream>>>(kb, qb, hnT, xT, accP, lpart);
    k_stats<<<N / 4, 256, 0, stream>>>(lpart, Ux, xb, mixing, stats);
    k_combine<<<(N * 512) / 1024, 256, 0, stream>>>(accP, stats, Uh, Ux, x, hmixb, outx);
    k_gemm16<1><<<512, 256, 0, stream>>>(hmixb, wvT, nullptr, h, outh);
}

// Round 12
// 399.741 us; speedup vs baseline: 1.0446x; 1.0446x over previous
//
#include <hip/hip_runtime.h>

#define N 8192
#define D 256

typedef unsigned short u16;
typedef unsigned int u32;
typedef short bf16x8 __attribute__((ext_vector_type(8)));
typedef float f32x4 __attribute__((ext_vector_type(4)));

__device__ __forceinline__ u16 f2bf(float f) {
    u32 u = __float_as_uint(f);
    u += 0x7FFFu + ((u >> 16) & 1u);
    return (u16)(u >> 16);
}
__device__ __forceinline__ float bf2f(u16 v) {
    return __uint_as_float(((u32)v) << 16);
}

#define MFMA(a, b, c) __builtin_amdgcn_mfma_f32_16x16x32_bf16((a), (b), (c), 0, 0, 0)

// ---------------- LayerNorm + bf16 casts: one wave per row ----------------
__global__ __launch_bounds__(256) void k_prep_ln(const float* __restrict__ h,
    const float* __restrict__ x, const float* __restrict__ gamma,
    const float* __restrict__ beta, u16* __restrict__ hnb, u16* __restrict__ xb)
{
    int lane = threadIdx.x & 63;
    int row = blockIdx.x * 4 + (threadIdx.x >> 6);
    const float4 hv = ((const float4*)(h + (size_t)row * D))[lane];
    float s = hv.x + hv.y + hv.z + hv.w;
    float s2 = hv.x * hv.x + hv.y * hv.y + hv.z * hv.z + hv.w * hv.w;
#pragma unroll
    for (int m = 1; m < 64; m <<= 1) { s += __shfl_xor(s, m); s2 += __shfl_xor(s2, m); }
    float mu = s * (1.0f / D);
    float var = s2 * (1.0f / D) - mu * mu;
    float rstd = rsqrtf(var + 1e-5f);
    const float4 gv = ((const float4*)gamma)[lane];
    const float4 bv = ((const float4*)beta)[lane];
    ushort4 o;
    o.x = f2bf((hv.x - mu) * rstd * gv.x + bv.x);
    o.y = f2bf((hv.y - mu) * rstd * gv.y + bv.y);
    o.z = f2bf((hv.z - mu) * rstd * gv.z + bv.z);
    o.w = f2bf((hv.w - mu) * rstd * gv.w + bv.w);
    ((ushort4*)(hnb + (size_t)row * D))[lane] = o;
    const float4 xv = ((const float4*)(x + (size_t)row * D))[lane];
    ushort4 xo;
    xo.x = f2bf(xv.x); xo.y = f2bf(xv.y); xo.z = f2bf(xv.z); xo.w = f2bf(xv.w);
    ((ushort4*)(xb + (size_t)row * D))[lane] = xo;
}

// ---------------- 256x256 f32 weight -> bf16 transpose ----------------
__global__ void k_wT(const float* __restrict__ Wk, const float* __restrict__ Wq,
                     const float* __restrict__ Wv, u16* __restrict__ wkT,
                     u16* __restrict__ wqT, u16* __restrict__ wvT)
{
    const float* src = blockIdx.y == 0 ? Wk : (blockIdx.y == 1 ? Wq : Wv);
    u16* dst = blockIdx.y == 0 ? wkT : (blockIdx.y == 1 ? wqT : wvT);
    int c = blockIdx.x, r = threadIdx.x;
    dst[c * D + r] = f2bf(src[r * D + c]);
}

// ---------------- [N][D] bf16 -> [D][N] bf16 transpose (LDS tiles) ----------------
__global__ __launch_bounds__(256) void k_transpose(const u16* __restrict__ s0,
    u16* __restrict__ d0, const u16* __restrict__ s1, u16* __restrict__ d1)
{
    const u16* src = blockIdx.y ? s1 : s0;
    u16* dst = blockIdx.y ? d1 : d0;
    int jb = (blockIdx.x & 127) * 64;
    int cb = (blockIdx.x >> 7) * 64;
    __shared__ u16 tile[64][72];
    int t = threadIdx.x;
#pragma unroll
    for (int i = 0; i < 2; ++i) {
        int id = t + i * 256;
        int r = id >> 3, ch = id & 7;
        uint4 v = *(const uint4*)(src + (size_t)(jb + r) * D + cb + ch * 8);
        *(uint4*)(&tile[r][ch * 8]) = v;
    }
    __syncthreads();
#pragma unroll
    for (int i = 0; i < 2; ++i) {
        int id = t + i * 256;
        int c = id >> 3, rch = id & 7;
        u16 vals[8] __attribute__((aligned(16)));
#pragma unroll
        for (int e = 0; e < 8; ++e) vals[e] = tile[rch * 8 + e][c];
        *(uint4*)(dst + (size_t)(cb + c) * N + jb + rch * 8) = *(const uint4*)vals;
    }
}

// ---------------- fused k&q projection: 16 rows/block, grid 512 ----------------
__global__ __launch_bounds__(256, 4) void k_proj_kq(const u16* __restrict__ A,
    const u16* __restrict__ wkT, const u16* __restrict__ wqT,
    u16* __restrict__ kb, u16* __restrict__ qb)
{
    int w = threadIdx.x >> 6;
    int lane = threadIdx.x & 63;
    int l16 = lane & 15, lhi = lane >> 4;
    int rows = blockIdx.x * 16;
    const u16* BT = (w >> 1) ? wqT : wkT;
    u16* out = (w >> 1) ? qb : kb;
    int colbase = (w & 1) * 128;
    const f32x4 z4 = {0.f, 0.f, 0.f, 0.f};
    f32x4 acc[8] = {z4, z4, z4, z4, z4, z4, z4, z4};
#pragma unroll
    for (int ks = 0; ks < 8; ++ks) {
        bf16x8 a = *(const bf16x8*)(A + (size_t)(rows + l16) * D + ks * 32 + lhi * 8);
#pragma unroll
        for (int cf = 0; cf < 8; ++cf) {
            bf16x8 b = *(const bf16x8*)(BT + (size_t)(colbase + cf * 16 + l16) * D + ks * 32 + lhi * 8);
            acc[cf] = MFMA(a, b, acc[cf]);
        }
    }
#pragma unroll
    for (int cf = 0; cf < 8; ++cf)
#pragma unroll
        for (int jj = 0; jj < 4; ++jj)
            out[(size_t)(rows + lhi * 4 + jj) * D + colbase + cf * 16 + l16] = f2bf(acc[cf][jj]);
}

// ---------------- small NT v2: 64-arow blocks, 4-pass in-register acc ----------------
// part[(z*2+side)][i][j] = sum_{n in slice z} P[i][n] * Q[j][n]
// grid (4, 2, 8): blockIdx.x = 64-arow block, y = side (0: x.x^T, 1: hn.x^T), z = n-slice.
// Q slice read ONCE per block (vs 16x in v1): traffic 139MB -> ~41MB.
__global__ __launch_bounds__(256) void k_small_nt(const u16* __restrict__ hnT,
    const u16* __restrict__ xT, float* __restrict__ part)
{
    const u16* P = blockIdx.y ? hnT : xT;
    const u16* Q = xT;
    int w = threadIdx.x >> 6;
    int lane = threadIdx.x & 63;
    int l16 = lane & 15, lhi = lane >> 4;
    int arow = blockIdx.x * 64;
    int bcol = w * 64;
    int n0b = blockIdx.z * 1024;
    const f32x4 z4 = {0.f, 0.f, 0.f, 0.f};
    f32x4 acc[4][4];
#pragma unroll
    for (int ap = 0; ap < 4; ++ap)
#pragma unroll
        for (int cf = 0; cf < 4; ++cf) acc[ap][cf] = z4;
    for (int n0 = n0b; n0 < n0b + 1024; n0 += 32) {
        bf16x8 b[4], a[4];
#pragma unroll
        for (int cf = 0; cf < 4; ++cf)
            b[cf] = *(const bf16x8*)(Q + (size_t)(bcol + cf * 16 + l16) * N + n0 + lhi * 8);
#pragma unroll
        for (int ap = 0; ap < 4; ++ap)
            a[ap] = *(const bf16x8*)(P + (size_t)(arow + ap * 16 + l16) * N + n0 + lhi * 8);
#pragma unroll
        for (int ap = 0; ap < 4; ++ap)
#pragma unroll
            for (int cf = 0; cf < 4; ++cf)
                acc[ap][cf] = MFMA(a[ap], b[cf], acc[ap][cf]);
    }
    float* dst = part + ((size_t)blockIdx.z * 2 + blockIdx.y) * 65536;
#pragma unroll
    for (int ap = 0; ap < 4; ++ap)
#pragma unroll
        for (int cf = 0; cf < 4; ++cf)
#pragma unroll
            for (int jj = 0; jj < 4; ++jj)
                dst[(size_t)(arow + ap * 16 + lhi * 4 + jj) * D + bcol + cf * 16 + l16] = acc[ap][cf][jj];
}

// ---------------- sum 8 k-slices + cast to bf16 ----------------
__global__ __launch_bounds__(256) void k_cast(const float* __restrict__ part,
    u16* __restrict__ Mb, u16* __restrict__ XHT)
{
    int t = blockIdx.x * 256 + threadIdx.x;   // 0..131071
    int side = t >> 16, idx = t & 65535;
    float s = 0.f;
#pragma unroll
    for (int ks = 0; ks < 8; ++ks) s += part[((size_t)ks * 2 + side) * 65536 + idx];
    (side ? XHT : Mb)[idx] = f2bf(s);
}

// ---------------- [N,256]@[256,256] 16-row GEMM; EPI 0: bf16 out, 1: elu+res f32 ----------------
template <int EPI>
__global__ __launch_bounds__(256, 4) void k_gemm16(const u16* __restrict__ A,
    const u16* __restrict__ BT, u16* __restrict__ outb,
    const float* __restrict__ res, float* __restrict__ outf)
{
    int w = threadIdx.x >> 6;
    int lane = threadIdx.x & 63;
    int l16 = lane & 15, lhi = lane >> 4;
    int rows = blockIdx.x * 16;
    int cols = w * 64;
    const f32x4 z4 = {0.f, 0.f, 0.f, 0.f};
    f32x4 acc[4] = {z4, z4, z4, z4};
#pragma unroll
    for (int ks = 0; ks < 8; ++ks) {
        bf16x8 a = *(const bf16x8*)(A + (size_t)(rows + l16) * D + ks * 32 + lhi * 8);
#pragma unroll
        for (int cf = 0; cf < 4; ++cf) {
            bf16x8 b = *(const bf16x8*)(BT + (size_t)(cols + cf * 16 + l16) * D + ks * 32 + lhi * 8);
            acc[cf] = MFMA(a, b, acc[cf]);
        }
    }
#pragma unroll
    for (int cf = 0; cf < 4; ++cf)
#pragma unroll
        for (int jj = 0; jj < 4; ++jj) {
            int r = rows + lhi * 4 + jj;
            int c = cols + cf * 16 + l16;
            float v = acc[cf][jj];
            if (EPI == 0) {
                outb[(size_t)r * D + c] = f2bf(v);
            } else {
                float z = v > 0.f ? v : expm1f(v);
                outf[(size_t)r * D + c] = z + res[(size_t)r * D + c];
            }
        }
}

// ---------------- fused S pass v9 (banked best): XOR AK swizzle, 2 barriers/iter ----------------
// grid 512: xcd = wgid&7, js = xcd>>1 (j-slice 2048), rb = (wgid>>3)*2+(xcd&1) (0..127), 64 rows.
// Per iter: phase1 computes P=exp(S/16) 64x256 into LDS (each wave 32rows x 32j x 2 subtiles);
// phase2 PV: 8 kf steps x 16 MFMA into 64x512 acc. Two lgkm-only barriers per iter.
// T prefetch issued BEFORE barrier B (in flight across it) — this placement is the win.
__global__ __launch_bounds__(512, 4) void k_fused(const u16* __restrict__ kb,
    const u16* __restrict__ qb, const u16* __restrict__ hnT,
    const u16* __restrict__ xT, u16* __restrict__ accP, float* __restrict__ lpart)
{
    __shared__ u16 AK[64 * 256];      // 32KB: K rows, XOR slot swizzle (matches read pattern)
    __shared__ u16 P[64 * 256];       // 32KB: P tile (single buffer), XOR row swizzle
    const int tid = threadIdx.x;
    const int w = tid >> 6;
    const int lane = tid & 63;
    const int l16 = lane & 15, lhi = lane >> 4;
    const int wgid = blockIdx.x;
    const int xcd = wgid & 7;
    const int js = xcd >> 1;
    const int rb = ((wgid >> 3) << 1) | (xcd & 1);
    const int R0 = rb * 64;
    const int jbase = js * 2048;

    // ---- stage AK: thread t -> row t>>3, logical slots (t&7)*4 .. +3,
    // physical slot = (s&16) | ((s&15) ^ (r&15))  (same involution on read) ----
    {
        int r = tid >> 3, sb = (tid & 7) * 4;
        const u16* src = kb + (size_t)(R0 + r) * D + sb * 8;
#pragma unroll
        for (int i = 0; i < 4; ++i) {
            bf16x8 v = *(const bf16x8*)(src + i * 8);
            int s = sb + i;
            int slotp = (s & 16) | ((s & 15) ^ (r & 15));
            *(bf16x8*)(AK + r * 256 + slotp * 8) = v;
        }
    }
    __syncthreads();

    // phase-1 role: rg = 32-row half (0..1), jf = 32-j chunk (0..3)
    const int rg = w & 1;
    const int jf = w >> 1;
    // phase-2 role: t2 = target (0=hn,1=x), ch = 64-col chunk (0..3)
    const int t2 = w >> 2;
    const int ch = w & 3;
    const u16* T = t2 ? xT : hnT;
    const u16* Tb0 = T + (size_t)(ch * 64 + 0 * 16 + l16) * N + lhi * 8;
    const u16* Tb1 = T + (size_t)(ch * 64 + 1 * 16 + l16) * N + lhi * 8;
    const u16* Tb2 = T + (size_t)(ch * 64 + 2 * 16 + l16) * N + lhi * 8;
    const u16* Tb3 = T + (size_t)(ch * 64 + 3 * 16 + l16) * N + lhi * 8;

    const f32x4 z4 = {0.f, 0.f, 0.f, 0.f};
    f32x4 acc[16];
#pragma unroll
    for (int i = 0; i < 16; ++i) acc[i] = z4;
    f32x4 red2[2] = {z4, z4};          // row-sum partials: red2[rf][jj]
    bf16x8 tp0[4], tp1[4];

    for (int it = 0; it < 8; ++it) {
        const int jb = jbase + it * 256;
        // barrier A: all phase-2 reads of P (prev iter) complete before overwrite
        asm volatile("s_waitcnt lgkmcnt(0)\n\ts_barrier" ::: "memory");

        // ---- phase 1: two 128-j subtiles; wave tile 32 rows x 32 j each ----
#pragma unroll
        for (int s = 0; s < 2; ++s) {
            const int jc = jb + s * 128 + jf * 32;
            f32x4 cs00 = z4, cs01 = z4, cs10 = z4, cs11 = z4;
#pragma unroll
            for (int ks = 0; ks < 8; ++ks) {
                int r0 = rg * 32 + l16;
                int r1 = r0 + 16;
                int sq = ks * 4 + lhi;
                int slx = (sq & 16) | ((sq & 15) ^ l16);   // r0&15 == r1&15 == l16
                bf16x8 a0 = *(const bf16x8*)(AK + r0 * 256 + slx * 8);
                bf16x8 a1 = *(const bf16x8*)(AK + r1 * 256 + slx * 8);
                const u16* Bq = qb + (size_t)(jc + l16) * D + ks * 32 + lhi * 8;
                bf16x8 b0 = *(const bf16x8*)(Bq);
                bf16x8 b1 = *(const bf16x8*)(Bq + 16 * D);
                cs00 = MFMA(a0, b0, cs00);
                cs01 = MFMA(a0, b1, cs01);
                cs10 = MFMA(a1, b0, cs10);
                cs11 = MFMA(a1, b1, cs11);
            }
#pragma unroll
            for (int rf = 0; rf < 2; ++rf)
#pragma unroll
                for (int cfr = 0; cfr < 2; ++cfr) {
                    f32x4 s4 = rf ? (cfr ? cs11 : cs10) : (cfr ? cs01 : cs00);
#pragma unroll
                    for (int jj = 0; jj < 4; ++jj) {
                        int row = rg * 32 + rf * 16 + lhi * 4 + jj;
                        int col = s * 128 + jf * 32 + cfr * 16 + l16;
                        float pv = __expf(s4[jj] * 0.0625f);
                        red2[rf][jj] += pv;
                        int slot = (col >> 3) ^ (row & 15);
                        *(u16*)((char*)P + row * 512 + slot * 16 + (col & 7) * 2) = f2bf(pv);
                    }
                }
        }
        // T prefetch for kf=0,1 — issued before barrier, stays in flight across it
        tp0[0] = *(const bf16x8*)(Tb0 + jb); tp0[1] = *(const bf16x8*)(Tb1 + jb);
        tp0[2] = *(const bf16x8*)(Tb2 + jb); tp0[3] = *(const bf16x8*)(Tb3 + jb);
        tp1[0] = *(const bf16x8*)(Tb0 + jb + 32); tp1[1] = *(const bf16x8*)(Tb1 + jb + 32);
        tp1[2] = *(const bf16x8*)(Tb2 + jb + 32); tp1[3] = *(const bf16x8*)(Tb3 + jb + 32);
        // barrier B: P writes visible
        asm volatile("s_waitcnt lgkmcnt(0)\n\ts_barrier" ::: "memory");

        // ---- phase 2: 8 kf steps (K=32 each), rolling depth-2 T prefetch ----
        __builtin_amdgcn_s_setprio(1);
        const char* Pb = (const char*)P;
#define PV_STEP(KF, TP)                                                             \
        {                                                                           \
            bf16x8 pa0 = *(const bf16x8*)(Pb + (0 * 16 + l16) * 512 + ((((KF) * 4 + lhi) ^ l16) << 4)); \
            bf16x8 pa1 = *(const bf16x8*)(Pb + (1 * 16 + l16) * 512 + ((((KF) * 4 + lhi) ^ l16) << 4)); \
            bf16x8 pa2 = *(const bf16x8*)(Pb + (2 * 16 + l16) * 512 + ((((KF) * 4 + lhi) ^ l16) << 4)); \
            bf16x8 pa3 = *(const bf16x8*)(Pb + (3 * 16 + l16) * 512 + ((((KF) * 4 + lhi) ^ l16) << 4)); \
            acc[0]  = MFMA(pa0, TP[0], acc[0]);  acc[1]  = MFMA(pa0, TP[1], acc[1]);  \
            acc[2]  = MFMA(pa0, TP[2], acc[2]);  acc[3]  = MFMA(pa0, TP[3], acc[3]);  \
            acc[4]  = MFMA(pa1, TP[0], acc[4]);  acc[5]  = MFMA(pa1, TP[1], acc[5]);  \
            acc[6]  = MFMA(pa1, TP[2], acc[6]);  acc[7]  = MFMA(pa1, TP[3], acc[7]);  \
            acc[8]  = MFMA(pa2, TP[0], acc[8]);  acc[9]  = MFMA(pa2, TP[1], acc[9]);  \
            acc[10] = MFMA(pa2, TP[2], acc[10]); acc[11] = MFMA(pa2, TP[3], acc[11]); \
            acc[12] = MFMA(pa3, TP[0], acc[12]); acc[13] = MFMA(pa3, TP[1], acc[13]); \
            acc[14] = MFMA(pa3, TP[2], acc[14]); acc[15] = MFMA(pa3, TP[3], acc[15]); \
            if ((KF) + 2 < 8) {                                                     \
                TP[0] = *(const bf16x8*)(Tb0 + jb + ((KF) + 2) * 32);               \
                TP[1] = *(const bf16x8*)(Tb1 + jb + ((KF) + 2) * 32);               \
                TP[2] = *(const bf16x8*)(Tb2 + jb + ((KF) + 2) * 32);               \
                TP[3] = *(const bf16x8*)(Tb3 + jb + ((KF) + 2) * 32);               \
            }                                                                       \
        }
        PV_STEP(0, tp0)
        PV_STEP(1, tp1)
        PV_STEP(2, tp0)
        PV_STEP(3, tp1)
        PV_STEP(4, tp0)
        PV_STEP(5, tp1)
        PV_STEP(6, tp0)
        PV_STEP(7, tp1)
#undef PV_STEP
        __builtin_amdgcn_s_setprio(0);
    }

    // ---- coalesced nontemporal partial store: wave-private [64 v][64 lane] bf16 ----
    {
        u16* base = accP + ((((size_t)js * 128 + rb) * 8 + w) * 64) * 64 + lane;
#pragma unroll
        for (int rf = 0; rf < 4; ++rf)
#pragma unroll
            for (int cf = 0; cf < 4; ++cf)
#pragma unroll
                for (int jj = 0; jj < 4; ++jj) {
                    int v = (rf * 4 + cf) * 4 + jj;
                    __builtin_nontemporal_store(f2bf(acc[rf * 4 + cf][jj]), base + (size_t)v * 64);
                }
    }
    // ---- softmax denominator partials (sum over this wave's 2x32 j columns) ----
#pragma unroll
    for (int rf = 0; rf < 2; ++rf)
#pragma unroll
        for (int m = 1; m < 16; m <<= 1) {
            red2[rf][0] += __shfl_xor(red2[rf][0], m);
            red2[rf][1] += __shfl_xor(red2[rf][1], m);
            red2[rf][2] += __shfl_xor(red2[rf][2], m);
            red2[rf][3] += __shfl_xor(red2[rf][3], m);
        }
    if (l16 == 0)
#pragma unroll
        for (int rf = 0; rf < 2; ++rf)
#pragma unroll
            for (int jj = 0; jj < 4; ++jj)
                atomicAdd(lpart + R0 + rg * 32 + rf * 16 + lhi * 4 + jj, red2[rf][jj]);
}

// ---------------- per-row stats: l, gn = sqrt(x.(xM)), mixing -> 4 scalars ----------------
__global__ __launch_bounds__(256) void k_stats(const float* __restrict__ lpart,
    const u16* __restrict__ Ux, const u16* __restrict__ xb,
    const float* __restrict__ mixing, float* __restrict__ stats)
{
    int lane = threadIdx.x & 63;
    int row = blockIdx.x * 4 + (threadIdx.x >> 6);
    float sg = 0.f;
    {
        ushort4 yv = ((const ushort4*)(Ux + (size_t)row * D))[lane];
        ushort4 xv = ((const ushort4*)(xb + (size_t)row * D))[lane];
        sg += bf2f(yv.x) * bf2f(xv.x);
        sg += bf2f(yv.y) * bf2f(xv.y);
        sg += bf2f(yv.z) * bf2f(xv.z);
        sg += bf2f(yv.w) * bf2f(xv.w);
    }
#pragma unroll
    for (int m = 1; m < 64; m <<= 1) sg += __shfl_xor(sg, m);
    if (lane == 0) {
        float inv_l = 1.0f / lpart[row];
        float inv_g = 1.0f / fmaxf(sqrtf(fmaxf(sg, 0.f)), 1e-12f);
        float e00 = __expf(mixing[0]), e10 = __expf(mixing[2]);
        float c00 = e00 / (e00 + e10), c10 = e10 / (e00 + e10);
        float e01 = __expf(mixing[1]), e11 = __expf(mixing[3]);
        float c01 = e01 / (e01 + e11), c11 = e11 / (e01 + e11);
        float4 stv = { c00 * inv_l, c10 * inv_g, c01 * inv_l, c11 * inv_g };
        ((float4*)stats)[row] = stv;
    }
}

// ---------------- combine: 4 wave-layout slices + rank-256 terms -> hmixb & x_new ----------------
__global__ __launch_bounds__(256) void k_combine(const u16* __restrict__ accP,
    const float* __restrict__ stats, const u16* __restrict__ Uh,
    const u16* __restrict__ Ux, const float* __restrict__ x0,
    u16* __restrict__ hmixb, float* __restrict__ outx)
{
    int t = blockIdx.x * 256 + threadIdx.x;
    int r = t >> 7;
    int q = t & 127;
    int rb = r >> 6, rr = r & 63;
    int t2 = q >> 6;
    int cc = (q & 63) * 4;                 // col within 256 of this target
    int wv = t2 * 4 + (cc >> 6);
    int rf = rr >> 4, lhi = (rr >> 2) & 3, jj = rr & 3;
    int cf = (cc >> 4) & 3, l16 = cc & 15;
    int v = (rf * 4 + cf) * 4 + jj;
    int lane = lhi * 16 + l16;
    float v0 = 0.f, v1 = 0.f, v2 = 0.f, v3 = 0.f;
#pragma unroll
    for (int s = 0; s < 4; ++s) {
        const u16* bp = accP + ((((size_t)s * 128 + rb) * 8 + wv) * 64 + v) * 64 + lane;
        ushort4 a = *(const ushort4*)bp;
        v0 += bf2f(a.x); v1 += bf2f(a.y); v2 += bf2f(a.z); v3 += bf2f(a.w);
    }
    float4 st = ((const float4*)stats)[r];
    if (t2 == 0) {
        int c = cc;
        ushort4 u = *(const ushort4*)(Uh + (size_t)r * D + c);
        ushort4 o;
        o.x = f2bf(st.x * v0 + st.y * bf2f(u.x));
        o.y = f2bf(st.x * v1 + st.y * bf2f(u.y));
        o.z = f2bf(st.x * v2 + st.y * bf2f(u.z));
        o.w = f2bf(st.x * v3 + st.y * bf2f(u.w));
        *(ushort4*)(hmixb + (size_t)r * D + c) = o;
    } else {
        int c = cc;
        ushort4 u = *(const ushort4*)(Ux + (size_t)r * D + c);
        float4 xv = *(const float4*)(x0 + (size_t)r * D + c);
        float4 o;
        o.x = st.z * v0 + st.w * bf2f(u.x) + xv.x;
        o.y = st.z * v1 + st.w * bf2f(u.y) + xv.y;
        o.z = st.z * v2 + st.w * bf2f(u.z) + xv.z;
        o.w = st.z * v3 + st.w * bf2f(u.w) + xv.w;
        *(float4*)(outx + (size_t)r * D + c) = o;
    }
}

extern "C" void kernel_launch(void* const* d_in, const int* in_sizes, int n_in,
                              void* d_out, int out_size, void* d_ws, size_t ws_size,
                              hipStream_t stream)
{
    const float* h = (const float*)d_in[0];
    const float* x = (const float*)d_in[1];
    const float* Wk = (const float*)d_in[2];
    const float* Wq = (const float*)d_in[3];
    const float* Wv = (const float*)d_in[4];
    const float* gamma = (const float*)d_in[5];
    const float* beta = (const float*)d_in[6];
    const float* mixing = (const float*)d_in[7];

    char* p = (char*)d_ws;
    const size_t ND2 = (size_t)N * D * 2;
    u16* hnb = (u16*)p; p += ND2;   // reused as Uh after k_proj_kq
    u16* xb = (u16*)p; p += ND2;
    u16* kb = (u16*)p; p += ND2;    // reused as hmixb after k_fused
    u16* qb = (u16*)p; p += ND2;
    u16* hnT = (u16*)p; p += ND2;
    u16* xT = (u16*)p; p += ND2;
    u16* Ux = (u16*)p; p += ND2;
    u16* wkT = (u16*)p; p += (size_t)D * D * 2;
    u16* wqT = (u16*)p; p += (size_t)D * D * 2;
    u16* wvT = (u16*)p; p += (size_t)D * D * 2;
    u16* Mb = (u16*)p; p += (size_t)D * D * 2;
    u16* XHT = (u16*)p; p += (size_t)D * D * 2;
    u16* accP = (u16*)p; p += (size_t)4 * N * 512 * 2;   // 32 MB bf16 wave-layout partials
    float* ntpart = (float*)accP;                        // overlay: used before accP
    float* lpart = (float*)p; p += (size_t)N * 4;
    float* stats = (float*)p; p += (size_t)N * 4 * 4;
    u16* Uh = hnb;      // overlay (hnb dead after k_proj_kq)
    u16* hmixb = kb;    // overlay (kb dead after k_fused)
    // total ~= 61 MB

    float* outh = (float*)d_out;
    float* outx = outh + (size_t)N * D;

    hipMemsetAsync(lpart, 0, (size_t)N * 4, stream);
    k_prep_ln<<<N / 4, 256, 0, stream>>>(h, x, gamma, beta, hnb, xb);
    k_wT<<<dim3(256, 3), 256, 0, stream>>>(Wk, Wq, Wv, wkT, wqT, wvT);
    k_transpose<<<dim3(512, 2), 256, 0, stream>>>(hnb, hnT, xb, xT);
    k_proj_kq<<<512, 256, 0, stream>>>(hnb, wkT, wqT, kb, qb);
    k_small_nt<<<dim3(4, 2, 8), 256, 0, stream>>>(hnT, xT, ntpart);
    k_cast<<<512, 256, 0, stream>>>(ntpart, Mb, XHT);
    k_gemm16<0><<<512, 256, 0, stream>>>(xb, Mb, Ux, nullptr, nullptr);
    k_gemm16<0><<<512, 256, 0, stream>>>(xb, XHT, Uh, nullptr, nullptr);
    k_fused<<<512, 512, 0, stream>>>(kb, qb, hnT, xT, accP, lpart);
    k_stats<<<N / 4, 256, 0, stream>>>(lpart, Ux, xb, mixing, stats);
    k_combine<<<(N * 512) / 1024, 256, 0, stream>>>(accP, stats, Uh, Ux, x, hmixb, outx);
    k_gemm16<1><<<512, 256, 0, stream>>>(hmixb, wvT, nullptr, h, outh);
}

// Round 13
// 375.266 us; speedup vs baseline: 1.1128x; 1.0652x over previous
//
#include <hip/hip_runtime.h>

#define N 8192
#define D 256

typedef unsigned short u16;
typedef unsigned int u32;
typedef short bf16x8 __attribute__((ext_vector_type(8)));
typedef float f32x4 __attribute__((ext_vector_type(4)));

__device__ __forceinline__ u16 f2bf(float f) {
    u32 u = __float_as_uint(f);
    u += 0x7FFFu + ((u >> 16) & 1u);
    return (u16)(u >> 16);
}
__device__ __forceinline__ float bf2f(u16 v) {
    return __uint_as_float(((u32)v) << 16);
}

#define MFMA(a, b, c) __builtin_amdgcn_mfma_f32_16x16x32_bf16((a), (b), (c), 0, 0, 0)

// ---------------- merged prep: blocks 0..2047 LayerNorm+casts; 2048..2815 weight transposes ----------------
__global__ __launch_bounds__(256) void k_prep_all(const float* __restrict__ h,
    const float* __restrict__ x, const float* __restrict__ gamma,
    const float* __restrict__ beta, u16* __restrict__ hnb, u16* __restrict__ xb,
    const float* __restrict__ Wk, const float* __restrict__ Wq,
    const float* __restrict__ Wv, u16* __restrict__ wkT,
    u16* __restrict__ wqT, u16* __restrict__ wvT)
{
    int bid = blockIdx.x;
    if (bid < 2048) {
        int lane = threadIdx.x & 63;
        int row = bid * 4 + (threadIdx.x >> 6);
        const float4 hv = ((const float4*)(h + (size_t)row * D))[lane];
        float s = hv.x + hv.y + hv.z + hv.w;
        float s2 = hv.x * hv.x + hv.y * hv.y + hv.z * hv.z + hv.w * hv.w;
#pragma unroll
        for (int m = 1; m < 64; m <<= 1) { s += __shfl_xor(s, m); s2 += __shfl_xor(s2, m); }
        float mu = s * (1.0f / D);
        float var = s2 * (1.0f / D) - mu * mu;
        float rstd = rsqrtf(var + 1e-5f);
        const float4 gv = ((const float4*)gamma)[lane];
        const float4 bv = ((const float4*)beta)[lane];
        ushort4 o;
        o.x = f2bf((hv.x - mu) * rstd * gv.x + bv.x);
        o.y = f2bf((hv.y - mu) * rstd * gv.y + bv.y);
        o.z = f2bf((hv.z - mu) * rstd * gv.z + bv.z);
        o.w = f2bf((hv.w - mu) * rstd * gv.w + bv.w);
        ((ushort4*)(hnb + (size_t)row * D))[lane] = o;
        const float4 xv = ((const float4*)(x + (size_t)row * D))[lane];
        ushort4 xo;
        xo.x = f2bf(xv.x); xo.y = f2bf(xv.y); xo.z = f2bf(xv.z); xo.w = f2bf(xv.w);
        ((ushort4*)(xb + (size_t)row * D))[lane] = xo;
    } else {
        int wid = bid - 2048;          // 0..767
        int sel = wid >> 8;            // 0..2
        int c = wid & 255;
        const float* src = sel == 0 ? Wk : (sel == 1 ? Wq : Wv);
        u16* dst = sel == 0 ? wkT : (sel == 1 ? wqT : wvT);
        int r = threadIdx.x;
        dst[c * D + r] = f2bf(src[r * D + c]);
    }
}

// ---------------- [N][D] bf16 -> [D][N] bf16 transpose (LDS tiles) ----------------
__global__ __launch_bounds__(256) void k_transpose(const u16* __restrict__ s0,
    u16* __restrict__ d0, const u16* __restrict__ s1, u16* __restrict__ d1)
{
    const u16* src = blockIdx.y ? s1 : s0;
    u16* dst = blockIdx.y ? d1 : d0;
    int jb = (blockIdx.x & 127) * 64;
    int cb = (blockIdx.x >> 7) * 64;
    __shared__ u16 tile[64][72];
    int t = threadIdx.x;
#pragma unroll
    for (int i = 0; i < 2; ++i) {
        int id = t + i * 256;
        int r = id >> 3, ch = id & 7;
        uint4 v = *(const uint4*)(src + (size_t)(jb + r) * D + cb + ch * 8);
        *(uint4*)(&tile[r][ch * 8]) = v;
    }
    __syncthreads();
#pragma unroll
    for (int i = 0; i < 2; ++i) {
        int id = t + i * 256;
        int c = id >> 3, rch = id & 7;
        u16 vals[8] __attribute__((aligned(16)));
#pragma unroll
        for (int e = 0; e < 8; ++e) vals[e] = tile[rch * 8 + e][c];
        *(uint4*)(dst + (size_t)(cb + c) * N + jb + rch * 8) = *(const uint4*)vals;
    }
}

// ---------------- fused k&q projection: 16 rows/block, grid 512 ----------------
__global__ __launch_bounds__(256, 4) void k_proj_kq(const u16* __restrict__ A,
    const u16* __restrict__ wkT, const u16* __restrict__ wqT,
    u16* __restrict__ kb, u16* __restrict__ qb)
{
    int w = threadIdx.x >> 6;
    int lane = threadIdx.x & 63;
    int l16 = lane & 15, lhi = lane >> 4;
    int rows = blockIdx.x * 16;
    const u16* BT = (w >> 1) ? wqT : wkT;
    u16* out = (w >> 1) ? qb : kb;
    int colbase = (w & 1) * 128;
    const f32x4 z4 = {0.f, 0.f, 0.f, 0.f};
    f32x4 acc[8] = {z4, z4, z4, z4, z4, z4, z4, z4};
#pragma unroll
    for (int ks = 0; ks < 8; ++ks) {
        bf16x8 a = *(const bf16x8*)(A + (size_t)(rows + l16) * D + ks * 32 + lhi * 8);
#pragma unroll
        for (int cf = 0; cf < 8; ++cf) {
            bf16x8 b = *(const bf16x8*)(BT + (size_t)(colbase + cf * 16 + l16) * D + ks * 32 + lhi * 8);
            acc[cf] = MFMA(a, b, acc[cf]);
        }
    }
#pragma unroll
    for (int cf = 0; cf < 8; ++cf)
#pragma unroll
        for (int jj = 0; jj < 4; ++jj)
            out[(size_t)(rows + lhi * 4 + jj) * D + colbase + cf * 16 + l16] = f2bf(acc[cf][jj]);
}

// ---------------- small NT v2': 64-arow blocks, 256-n slices, grid (4,2,32) ----------------
// part[(z*2+side)][i][j] = sum_{n in slice z} P[i][n] * Q[j][n]
__global__ __launch_bounds__(256) void k_small_nt(const u16* __restrict__ hnT,
    const u16* __restrict__ xT, float* __restrict__ part)
{
    const u16* P = blockIdx.y ? hnT : xT;
    const u16* Q = xT;
    int w = threadIdx.x >> 6;
    int lane = threadIdx.x & 63;
    int l16 = lane & 15, lhi = lane >> 4;
    int arow = blockIdx.x * 64;
    int bcol = w * 64;
    int n0b = blockIdx.z * 256;
    const f32x4 z4 = {0.f, 0.f, 0.f, 0.f};
    f32x4 acc[4][4];
#pragma unroll
    for (int ap = 0; ap < 4; ++ap)
#pragma unroll
        for (int cf = 0; cf < 4; ++cf) acc[ap][cf] = z4;
    for (int n0 = n0b; n0 < n0b + 256; n0 += 32) {
        bf16x8 b[4], a[4];
#pragma unroll
        for (int cf = 0; cf < 4; ++cf)
            b[cf] = *(const bf16x8*)(Q + (size_t)(bcol + cf * 16 + l16) * N + n0 + lhi * 8);
#pragma unroll
        for (int ap = 0; ap < 4; ++ap)
            a[ap] = *(const bf16x8*)(P + (size_t)(arow + ap * 16 + l16) * N + n0 + lhi * 8);
#pragma unroll
        for (int ap = 0; ap < 4; ++ap)
#pragma unroll
            for (int cf = 0; cf < 4; ++cf)
                acc[ap][cf] = MFMA(a[ap], b[cf], acc[ap][cf]);
    }
    float* dst = part + ((size_t)blockIdx.z * 2 + blockIdx.y) * 65536;
#pragma unroll
    for (int ap = 0; ap < 4; ++ap)
#pragma unroll
        for (int cf = 0; cf < 4; ++cf)
#pragma unroll
            for (int jj = 0; jj < 4; ++jj)
                dst[(size_t)(arow + ap * 16 + lhi * 4 + jj) * D + bcol + cf * 16 + l16] = acc[ap][cf][jj];
}

// ---------------- sum 32 n-slices + cast to bf16 ----------------
__global__ __launch_bounds__(256) void k_cast(const float* __restrict__ part,
    u16* __restrict__ Mb, u16* __restrict__ XHT)
{
    int t = blockIdx.x * 256 + threadIdx.x;   // 0..131071
    int side = t >> 16, idx = t & 65535;
    float s = 0.f;
#pragma unroll
    for (int ks = 0; ks < 32; ++ks) s += part[((size_t)ks * 2 + side) * 65536 + idx];
    (side ? XHT : Mb)[idx] = f2bf(s);
}

// ---------------- dual 16-row GEMM (both rank-256 products in one launch) ----------------
__global__ __launch_bounds__(256, 4) void k_gemm16_dual(const u16* __restrict__ A,
    const u16* __restrict__ BT0, const u16* __restrict__ BT1,
    u16* __restrict__ out0, u16* __restrict__ out1)
{
    const u16* BT = blockIdx.y ? BT1 : BT0;
    u16* outb = blockIdx.y ? out1 : out0;
    int w = threadIdx.x >> 6;
    int lane = threadIdx.x & 63;
    int l16 = lane & 15, lhi = lane >> 4;
    int rows = blockIdx.x * 16;
    int cols = w * 64;
    const f32x4 z4 = {0.f, 0.f, 0.f, 0.f};
    f32x4 acc[4] = {z4, z4, z4, z4};
#pragma unroll
    for (int ks = 0; ks < 8; ++ks) {
        bf16x8 a = *(const bf16x8*)(A + (size_t)(rows + l16) * D + ks * 32 + lhi * 8);
#pragma unroll
        for (int cf = 0; cf < 4; ++cf) {
            bf16x8 b = *(const bf16x8*)(BT + (size_t)(cols + cf * 16 + l16) * D + ks * 32 + lhi * 8);
            acc[cf] = MFMA(a, b, acc[cf]);
        }
    }
#pragma unroll
    for (int cf = 0; cf < 4; ++cf)
#pragma unroll
        for (int jj = 0; jj < 4; ++jj)
            outb[(size_t)(rows + lhi * 4 + jj) * D + cols + cf * 16 + l16] = f2bf(acc[cf][jj]);
}

// ---------------- final GEMM: elu + residual, f32 out ----------------
__global__ __launch_bounds__(256, 4) void k_gemm16_elu(const u16* __restrict__ A,
    const u16* __restrict__ BT, const float* __restrict__ res, float* __restrict__ outf)
{
    int w = threadIdx.x >> 6;
    int lane = threadIdx.x & 63;
    int l16 = lane & 15, lhi = lane >> 4;
    int rows = blockIdx.x * 16;
    int cols = w * 64;
    const f32x4 z4 = {0.f, 0.f, 0.f, 0.f};
    f32x4 acc[4] = {z4, z4, z4, z4};
#pragma unroll
    for (int ks = 0; ks < 8; ++ks) {
        bf16x8 a = *(const bf16x8*)(A + (size_t)(rows + l16) * D + ks * 32 + lhi * 8);
#pragma unroll
        for (int cf = 0; cf < 4; ++cf) {
            bf16x8 b = *(const bf16x8*)(BT + (size_t)(cols + cf * 16 + l16) * D + ks * 32 + lhi * 8);
            acc[cf] = MFMA(a, b, acc[cf]);
        }
    }
#pragma unroll
    for (int cf = 0; cf < 4; ++cf)
#pragma unroll
        for (int jj = 0; jj < 4; ++jj) {
            int r = rows + lhi * 4 + jj;
            int c = cols + cf * 16 + l16;
            float v = acc[cf][jj];
            float z = v > 0.f ? v : expm1f(v);
            outf[(size_t)r * D + c] = z + res[(size_t)r * D + c];
        }
}

// ---------------- fused S pass v9 (banked best): XOR AK swizzle, 2 barriers/iter ----------------
__global__ __launch_bounds__(512, 4) void k_fused(const u16* __restrict__ kb,
    const u16* __restrict__ qb, const u16* __restrict__ hnT,
    const u16* __restrict__ xT, u16* __restrict__ accP, float* __restrict__ lpart)
{
    __shared__ u16 AK[64 * 256];      // 32KB: K rows, XOR slot swizzle (matches read pattern)
    __shared__ u16 P[64 * 256];       // 32KB: P tile (single buffer), XOR row swizzle
    const int tid = threadIdx.x;
    const int w = tid >> 6;
    const int lane = tid & 63;
    const int l16 = lane & 15, lhi = lane >> 4;
    const int wgid = blockIdx.x;
    const int xcd = wgid & 7;
    const int js = xcd >> 1;
    const int rb = ((wgid >> 3) << 1) | (xcd & 1);
    const int R0 = rb * 64;
    const int jbase = js * 2048;

    // ---- stage AK: physical slot = (s&16) | ((s&15) ^ (r&15)) ----
    {
        int r = tid >> 3, sb = (tid & 7) * 4;
        const u16* src = kb + (size_t)(R0 + r) * D + sb * 8;
#pragma unroll
        for (int i = 0; i < 4; ++i) {
            bf16x8 v = *(const bf16x8*)(src + i * 8);
            int s = sb + i;
            int slotp = (s & 16) | ((s & 15) ^ (r & 15));
            *(bf16x8*)(AK + r * 256 + slotp * 8) = v;
        }
    }
    __syncthreads();

    const int rg = w & 1;
    const int jf = w >> 1;
    const int t2 = w >> 2;
    const int ch = w & 3;
    const u16* T = t2 ? xT : hnT;
    const u16* Tb0 = T + (size_t)(ch * 64 + 0 * 16 + l16) * N + lhi * 8;
    const u16* Tb1 = T + (size_t)(ch * 64 + 1 * 16 + l16) * N + lhi * 8;
    const u16* Tb2 = T + (size_t)(ch * 64 + 2 * 16 + l16) * N + lhi * 8;
    const u16* Tb3 = T + (size_t)(ch * 64 + 3 * 16 + l16) * N + lhi * 8;

    const f32x4 z4 = {0.f, 0.f, 0.f, 0.f};
    f32x4 acc[16];
#pragma unroll
    for (int i = 0; i < 16; ++i) acc[i] = z4;
    f32x4 red2[2] = {z4, z4};
    bf16x8 tp0[4], tp1[4];

    for (int it = 0; it < 8; ++it) {
        const int jb = jbase + it * 256;
        asm volatile("s_waitcnt lgkmcnt(0)\n\ts_barrier" ::: "memory");

        // ---- phase 1: two 128-j subtiles; wave tile 32 rows x 32 j each ----
#pragma unroll
        for (int s = 0; s < 2; ++s) {
            const int jc = jb + s * 128 + jf * 32;
            f32x4 cs00 = z4, cs01 = z4, cs10 = z4, cs11 = z4;
#pragma unroll
            for (int ks = 0; ks < 8; ++ks) {
                int r0 = rg * 32 + l16;
                int r1 = r0 + 16;
                int sq = ks * 4 + lhi;
                int slx = (sq & 16) | ((sq & 15) ^ l16);
                bf16x8 a0 = *(const bf16x8*)(AK + r0 * 256 + slx * 8);
                bf16x8 a1 = *(const bf16x8*)(AK + r1 * 256 + slx * 8);
                const u16* Bq = qb + (size_t)(jc + l16) * D + ks * 32 + lhi * 8;
                bf16x8 b0 = *(const bf16x8*)(Bq);
                bf16x8 b1 = *(const bf16x8*)(Bq + 16 * D);
                cs00 = MFMA(a0, b0, cs00);
                cs01 = MFMA(a0, b1, cs01);
                cs10 = MFMA(a1, b0, cs10);
                cs11 = MFMA(a1, b1, cs11);
            }
#pragma unroll
            for (int rf = 0; rf < 2; ++rf)
#pragma unroll
                for (int cfr = 0; cfr < 2; ++cfr) {
                    f32x4 s4 = rf ? (cfr ? cs11 : cs10) : (cfr ? cs01 : cs00);
#pragma unroll
                    for (int jj = 0; jj < 4; ++jj) {
                        int row = rg * 32 + rf * 16 + lhi * 4 + jj;
                        int col = s * 128 + jf * 32 + cfr * 16 + l16;
                        float pv = __expf(s4[jj] * 0.0625f);
                        red2[rf][jj] += pv;
                        int slot = (col >> 3) ^ (row & 15);
                        *(u16*)((char*)P + row * 512 + slot * 16 + (col & 7) * 2) = f2bf(pv);
                    }
                }
        }
        // T prefetch for kf=0,1 — issued before barrier, stays in flight across it
        tp0[0] = *(const bf16x8*)(Tb0 + jb); tp0[1] = *(const bf16x8*)(Tb1 + jb);
        tp0[2] = *(const bf16x8*)(Tb2 + jb); tp0[3] = *(const bf16x8*)(Tb3 + jb);
        tp1[0] = *(const bf16x8*)(Tb0 + jb + 32); tp1[1] = *(const bf16x8*)(Tb1 + jb + 32);
        tp1[2] = *(const bf16x8*)(Tb2 + jb + 32); tp1[3] = *(const bf16x8*)(Tb3 + jb + 32);
        asm volatile("s_waitcnt lgkmcnt(0)\n\ts_barrier" ::: "memory");

        // ---- phase 2: 8 kf steps (K=32 each), rolling depth-2 T prefetch ----
        __builtin_amdgcn_s_setprio(1);
        const char* Pb = (const char*)P;
#define PV_STEP(KF, TP)                                                             \
        {                                                                           \
            bf16x8 pa0 = *(const bf16x8*)(Pb + (0 * 16 + l16) * 512 + ((((KF) * 4 + lhi) ^ l16) << 4)); \
            bf16x8 pa1 = *(const bf16x8*)(Pb + (1 * 16 + l16) * 512 + ((((KF) * 4 + lhi) ^ l16) << 4)); \
            bf16x8 pa2 = *(const bf16x8*)(Pb + (2 * 16 + l16) * 512 + ((((KF) * 4 + lhi) ^ l16) << 4)); \
            bf16x8 pa3 = *(const bf16x8*)(Pb + (3 * 16 + l16) * 512 + ((((KF) * 4 + lhi) ^ l16) << 4)); \
            acc[0]  = MFMA(pa0, TP[0], acc[0]);  acc[1]  = MFMA(pa0, TP[1], acc[1]);  \
            acc[2]  = MFMA(pa0, TP[2], acc[2]);  acc[3]  = MFMA(pa0, TP[3], acc[3]);  \
            acc[4]  = MFMA(pa1, TP[0], acc[4]);  acc[5]  = MFMA(pa1, TP[1], acc[5]);  \
            acc[6]  = MFMA(pa1, TP[2], acc[6]);  acc[7]  = MFMA(pa1, TP[3], acc[7]);  \
            acc[8]  = MFMA(pa2, TP[0], acc[8]);  acc[9]  = MFMA(pa2, TP[1], acc[9]);  \
            acc[10] = MFMA(pa2, TP[2], acc[10]); acc[11] = MFMA(pa2, TP[3], acc[11]); \
            acc[12] = MFMA(pa3, TP[0], acc[12]); acc[13] = MFMA(pa3, TP[1], acc[13]); \
            acc[14] = MFMA(pa3, TP[2], acc[14]); acc[15] = MFMA(pa3, TP[3], acc[15]); \
            if ((KF) + 2 < 8) {                                                     \
                TP[0] = *(const bf16x8*)(Tb0 + jb + ((KF) + 2) * 32);               \
                TP[1] = *(const bf16x8*)(Tb1 + jb + ((KF) + 2) * 32);               \
                TP[2] = *(const bf16x8*)(Tb2 + jb + ((KF) + 2) * 32);               \
                TP[3] = *(const bf16x8*)(Tb3 + jb + ((KF) + 2) * 32);               \
            }                                                                       \
        }
        PV_STEP(0, tp0)
        PV_STEP(1, tp1)
        PV_STEP(2, tp0)
        PV_STEP(3, tp1)
        PV_STEP(4, tp0)
        PV_STEP(5, tp1)
        PV_STEP(6, tp0)
        PV_STEP(7, tp1)
#undef PV_STEP
        __builtin_amdgcn_s_setprio(0);
    }

    // ---- coalesced nontemporal partial store: wave-private [64 v][64 lane] bf16 ----
    {
        u16* base = accP + ((((size_t)js * 128 + rb) * 8 + w) * 64) * 64 + lane;
#pragma unroll
        for (int rf = 0; rf < 4; ++rf)
#pragma unroll
            for (int cf = 0; cf < 4; ++cf)
#pragma unroll
                for (int jj = 0; jj < 4; ++jj) {
                    int v = (rf * 4 + cf) * 4 + jj;
                    __builtin_nontemporal_store(f2bf(acc[rf * 4 + cf][jj]), base + (size_t)v * 64);
                }
    }
    // ---- softmax denominator partials ----
#pragma unroll
    for (int rf = 0; rf < 2; ++rf)
#pragma unroll
        for (int m = 1; m < 16; m <<= 1) {
            red2[rf][0] += __shfl_xor(red2[rf][0], m);
            red2[rf][1] += __shfl_xor(red2[rf][1], m);
            red2[rf][2] += __shfl_xor(red2[rf][2], m);
            red2[rf][3] += __shfl_xor(red2[rf][3], m);
        }
    if (l16 == 0)
#pragma unroll
        for (int rf = 0; rf < 2; ++rf)
#pragma unroll
            for (int jj = 0; jj < 4; ++jj)
                atomicAdd(lpart + R0 + rg * 32 + rf * 16 + lhi * 4 + jj, red2[rf][jj]);
}

// ---------------- per-row stats: l, gn = sqrt(x.(xM)), mixing -> 4 scalars ----------------
__global__ __launch_bounds__(256) void k_stats(const float* __restrict__ lpart,
    const u16* __restrict__ Ux, const u16* __restrict__ xb,
    const float* __restrict__ mixing, float* __restrict__ stats)
{
    int lane = threadIdx.x & 63;
    int row = blockIdx.x * 4 + (threadIdx.x >> 6);
    float sg = 0.f;
    {
        ushort4 yv = ((const ushort4*)(Ux + (size_t)row * D))[lane];
        ushort4 xv = ((const ushort4*)(xb + (size_t)row * D))[lane];
        sg += bf2f(yv.x) * bf2f(xv.x);
        sg += bf2f(yv.y) * bf2f(xv.y);
        sg += bf2f(yv.z) * bf2f(xv.z);
        sg += bf2f(yv.w) * bf2f(xv.w);
    }
#pragma unroll
    for (int m = 1; m < 64; m <<= 1) sg += __shfl_xor(sg, m);
    if (lane == 0) {
        float inv_l = 1.0f / lpart[row];
        float inv_g = 1.0f / fmaxf(sqrtf(fmaxf(sg, 0.f)), 1e-12f);
        float e00 = __expf(mixing[0]), e10 = __expf(mixing[2]);
        float c00 = e00 / (e00 + e10), c10 = e10 / (e00 + e10);
        float e01 = __expf(mixing[1]), e11 = __expf(mixing[3]);
        float c01 = e01 / (e01 + e11), c11 = e11 / (e01 + e11);
        float4 stv = { c00 * inv_l, c10 * inv_g, c01 * inv_l, c11 * inv_g };
        ((float4*)stats)[row] = stv;
    }
}

// ---------------- combine: 4 wave-layout slices + rank-256 terms -> hmixb & x_new ----------------
__global__ __launch_bounds__(256) void k_combine(const u16* __restrict__ accP,
    const float* __restrict__ stats, const u16* __restrict__ Uh,
    const u16* __restrict__ Ux, const float* __restrict__ x0,
    u16* __restrict__ hmixb, float* __restrict__ outx)
{
    int t = blockIdx.x * 256 + threadIdx.x;
    int r = t >> 7;
    int q = t & 127;
    int rb = r >> 6, rr = r & 63;
    int t2 = q >> 6;
    int cc = (q & 63) * 4;
    int wv = t2 * 4 + (cc >> 6);
    int rf = rr >> 4, lhi = (rr >> 2) & 3, jj = rr & 3;
    int cf = (cc >> 4) & 3, l16 = cc & 15;
    int v = (rf * 4 + cf) * 4 + jj;
    int lane = lhi * 16 + l16;
    float v0 = 0.f, v1 = 0.f, v2 = 0.f, v3 = 0.f;
#pragma unroll
    for (int s = 0; s < 4; ++s) {
        const u16* bp = accP + ((((size_t)s * 128 + rb) * 8 + wv) * 64 + v) * 64 + lane;
        ushort4 a = *(const ushort4*)bp;
        v0 += bf2f(a.x); v1 += bf2f(a.y); v2 += bf2f(a.z); v3 += bf2f(a.w);
    }
    float4 st = ((const float4*)stats)[r];
    if (t2 == 0) {
        int c = cc;
        ushort4 u = *(const ushort4*)(Uh + (size_t)r * D + c);
        ushort4 o;
        o.x = f2bf(st.x * v0 + st.y * bf2f(u.x));
        o.y = f2bf(st.x * v1 + st.y * bf2f(u.y));
        o.z = f2bf(st.x * v2 + st.y * bf2f(u.z));
        o.w = f2bf(st.x * v3 + st.y * bf2f(u.w));
        *(ushort4*)(hmixb + (size_t)r * D + c) = o;
    } else {
        int c = cc;
        ushort4 u = *(const ushort4*)(Ux + (size_t)r * D + c);
        float4 xv = *(const float4*)(x0 + (size_t)r * D + c);
        float4 o;
        o.x = st.z * v0 + st.w * bf2f(u.x) + xv.x;
        o.y = st.z * v1 + st.w * bf2f(u.y) + xv.y;
        o.z = st.z * v2 + st.w * bf2f(u.z) + xv.z;
        o.w = st.z * v3 + st.w * bf2f(u.w) + xv.w;
        *(float4*)(outx + (size_t)r * D + c) = o;
    }
}

extern "C" void kernel_launch(void* const* d_in, const int* in_sizes, int n_in,
                              void* d_out, int out_size, void* d_ws, size_t ws_size,
                              hipStream_t stream)
{
    const float* h = (const float*)d_in[0];
    const float* x = (const float*)d_in[1];
    const float* Wk = (const float*)d_in[2];
    const float* Wq = (const float*)d_in[3];
    const float* Wv = (const float*)d_in[4];
    const float* gamma = (const float*)d_in[5];
    const float* beta = (const float*)d_in[6];
    const float* mixing = (const float*)d_in[7];

    char* p = (char*)d_ws;
    const size_t ND2 = (size_t)N * D * 2;
    u16* hnb = (u16*)p; p += ND2;   // reused as Uh after k_proj_kq
    u16* xb = (u16*)p; p += ND2;
    u16* kb = (u16*)p; p += ND2;    // reused as hmixb after k_fused
    u16* qb = (u16*)p; p += ND2;
    u16* hnT = (u16*)p; p += ND2;
    u16* xT = (u16*)p; p += ND2;
    u16* Ux = (u16*)p; p += ND2;
    u16* wkT = (u16*)p; p += (size_t)D * D * 2;
    u16* wqT = (u16*)p; p += (size_t)D * D * 2;
    u16* wvT = (u16*)p; p += (size_t)D * D * 2;
    u16* Mb = (u16*)p; p += (size_t)D * D * 2;
    u16* XHT = (u16*)p; p += (size_t)D * D * 2;
    u16* accP = (u16*)p; p += (size_t)4 * N * 512 * 2;   // 32 MB bf16 wave-layout partials
    float* ntpart = (float*)accP;                        // overlay: 64 x 65536 f32 = 16MB, used before accP
    float* lpart = (float*)p; p += (size_t)N * 4;
    float* stats = (float*)p; p += (size_t)N * 4 * 4;
    u16* Uh = hnb;      // overlay (hnb dead after k_proj_kq)
    u16* hmixb = kb;    // overlay (kb dead after k_fused)
    // total ~= 61 MB

    float* outh = (float*)d_out;
    float* outx = outh + (size_t)N * D;

    hipMemsetAsync(lpart, 0, (size_t)N * 4, stream);
    k_prep_all<<<2048 + 768, 256, 0, stream>>>(h, x, gamma, beta, hnb, xb,
                                               Wk, Wq, Wv, wkT, wqT, wvT);
    k_transpose<<<dim3(512, 2), 256, 0, stream>>>(hnb, hnT, xb, xT);
    k_proj_kq<<<512, 256, 0, stream>>>(hnb, wkT, wqT, kb, qb);
    k_small_nt<<<dim3(4, 2, 32), 256, 0, stream>>>(hnT, xT, ntpart);
    k_cast<<<512, 256, 0, stream>>>(ntpart, Mb, XHT);
    k_gemm16_dual<<<dim3(512, 2), 256, 0, stream>>>(xb, Mb, XHT, Ux, Uh);
    k_fused<<<512, 512, 0, stream>>>(kb, qb, hnT, xT, accP, lpart);
    k_stats<<<N / 4, 256, 0, stream>>>(lpart, Ux, xb, mixing, stats);
    k_combine<<<(N * 512) / 1024, 256, 0, stream>>>(accP, stats, Uh, Ux, x, hmixb, outx);
    k_gemm16_elu<<<512, 256, 0, stream>>>(hmixb, wvT, h, outh);
}

// Round 14
// 367.225 us; speedup vs baseline: 1.1371x; 1.0219x over previous
//
#include <hip/hip_runtime.h>

#define N 8192
#define D 256

typedef unsigned short u16;
typedef unsigned int u32;
typedef short bf16x8 __attribute__((ext_vector_type(8)));
typedef float f32x4 __attribute__((ext_vector_type(4)));

__device__ __forceinline__ u16 f2bf(float f) {
    u32 u = __float_as_uint(f);
    u += 0x7FFFu + ((u >> 16) & 1u);
    return (u16)(u >> 16);
}
__device__ __forceinline__ float bf2f(u16 v) {
    return __uint_as_float(((u32)v) << 16);
}

#define MFMA(a, b, c) __builtin_amdgcn_mfma_f32_16x16x32_bf16((a), (b), (c), 0, 0, 0)

// ---------------- merged prep: blocks 0..2047 LayerNorm+casts; 2048..2815 weight transposes ----------------
__global__ __launch_bounds__(256) void k_prep_all(const float* __restrict__ h,
    const float* __restrict__ x, const float* __restrict__ gamma,
    const float* __restrict__ beta, u16* __restrict__ hnb, u16* __restrict__ xb,
    const float* __restrict__ Wk, const float* __restrict__ Wq,
    const float* __restrict__ Wv, u16* __restrict__ wkT,
    u16* __restrict__ wqT, u16* __restrict__ wvT)
{
    int bid = blockIdx.x;
    if (bid < 2048) {
        int lane = threadIdx.x & 63;
        int row = bid * 4 + (threadIdx.x >> 6);
        const float4 hv = ((const float4*)(h + (size_t)row * D))[lane];
        float s = hv.x + hv.y + hv.z + hv.w;
        float s2 = hv.x * hv.x + hv.y * hv.y + hv.z * hv.z + hv.w * hv.w;
#pragma unroll
        for (int m = 1; m < 64; m <<= 1) { s += __shfl_xor(s, m); s2 += __shfl_xor(s2, m); }
        float mu = s * (1.0f / D);
        float var = s2 * (1.0f / D) - mu * mu;
        float rstd = rsqrtf(var + 1e-5f);
        const float4 gv = ((const float4*)gamma)[lane];
        const float4 bv = ((const float4*)beta)[lane];
        ushort4 o;
        o.x = f2bf((hv.x - mu) * rstd * gv.x + bv.x);
        o.y = f2bf((hv.y - mu) * rstd * gv.y + bv.y);
        o.z = f2bf((hv.z - mu) * rstd * gv.z + bv.z);
        o.w = f2bf((hv.w - mu) * rstd * gv.w + bv.w);
        ((ushort4*)(hnb + (size_t)row * D))[lane] = o;
        const float4 xv = ((const float4*)(x + (size_t)row * D))[lane];
        ushort4 xo;
        xo.x = f2bf(xv.x); xo.y = f2bf(xv.y); xo.z = f2bf(xv.z); xo.w = f2bf(xv.w);
        ((ushort4*)(xb + (size_t)row * D))[lane] = xo;
    } else {
        int wid = bid - 2048;          // 0..767
        int sel = wid >> 8;            // 0..2
        int c = wid & 255;
        const float* src = sel == 0 ? Wk : (sel == 1 ? Wq : Wv);
        u16* dst = sel == 0 ? wkT : (sel == 1 ? wqT : wvT);
        int r = threadIdx.x;
        dst[c * D + r] = f2bf(src[r * D + c]);
    }
}

// ---------------- merged: blocks 0..1023 bf16 transpose; 1024..1535 k&q projection ----------------
__global__ __launch_bounds__(256, 4) void k_trans_proj(const u16* __restrict__ hnb,
    u16* __restrict__ hnT, const u16* __restrict__ xb, u16* __restrict__ xT,
    const u16* __restrict__ wkT, const u16* __restrict__ wqT,
    u16* __restrict__ kb, u16* __restrict__ qb)
{
    __shared__ u16 tile[64][72];
    int bid = blockIdx.x;
    if (bid < 1024) {
        const u16* src = (bid >> 9) ? xb : hnb;
        u16* dst = (bid >> 9) ? xT : hnT;
        int xx = bid & 511;
        int jb = (xx & 127) * 64;
        int cb = (xx >> 7) * 64;
        int t = threadIdx.x;
#pragma unroll
        for (int i = 0; i < 2; ++i) {
            int id = t + i * 256;
            int r = id >> 3, ch = id & 7;
            uint4 v = *(const uint4*)(src + (size_t)(jb + r) * D + cb + ch * 8);
            *(uint4*)(&tile[r][ch * 8]) = v;
        }
        __syncthreads();
#pragma unroll
        for (int i = 0; i < 2; ++i) {
            int id = t + i * 256;
            int c = id >> 3, rch = id & 7;
            u16 vals[8] __attribute__((aligned(16)));
#pragma unroll
            for (int e = 0; e < 8; ++e) vals[e] = tile[rch * 8 + e][c];
            *(uint4*)(dst + (size_t)(cb + c) * N + jb + rch * 8) = *(const uint4*)vals;
        }
    } else {
        int pb = bid - 1024;           // 0..511
        int w = threadIdx.x >> 6;
        int lane = threadIdx.x & 63;
        int l16 = lane & 15, lhi = lane >> 4;
        int rows = pb * 16;
        const u16* BT = (w >> 1) ? wqT : wkT;
        u16* out = (w >> 1) ? qb : kb;
        int colbase = (w & 1) * 128;
        const f32x4 z4 = {0.f, 0.f, 0.f, 0.f};
        f32x4 acc[8] = {z4, z4, z4, z4, z4, z4, z4, z4};
#pragma unroll
        for (int ks = 0; ks < 8; ++ks) {
            bf16x8 a = *(const bf16x8*)(hnb + (size_t)(rows + l16) * D + ks * 32 + lhi * 8);
#pragma unroll
            for (int cf = 0; cf < 8; ++cf) {
                bf16x8 b = *(const bf16x8*)(BT + (size_t)(colbase + cf * 16 + l16) * D + ks * 32 + lhi * 8);
                acc[cf] = MFMA(a, b, acc[cf]);
            }
        }
#pragma unroll
        for (int cf = 0; cf < 8; ++cf)
#pragma unroll
            for (int jj = 0; jj < 4; ++jj)
                out[(size_t)(rows + lhi * 4 + jj) * D + colbase + cf * 16 + l16] = f2bf(acc[cf][jj]);
    }
}

// ---------------- small NT v2': 64-arow blocks, 256-n slices, grid (4,2,32) ----------------
__global__ __launch_bounds__(256) void k_small_nt(const u16* __restrict__ hnT,
    const u16* __restrict__ xT, float* __restrict__ part)
{
    const u16* P = blockIdx.y ? hnT : xT;
    const u16* Q = xT;
    int w = threadIdx.x >> 6;
    int lane = threadIdx.x & 63;
    int l16 = lane & 15, lhi = lane >> 4;
    int arow = blockIdx.x * 64;
    int bcol = w * 64;
    int n0b = blockIdx.z * 256;
    const f32x4 z4 = {0.f, 0.f, 0.f, 0.f};
    f32x4 acc[4][4];
#pragma unroll
    for (int ap = 0; ap < 4; ++ap)
#pragma unroll
        for (int cf = 0; cf < 4; ++cf) acc[ap][cf] = z4;
    for (int n0 = n0b; n0 < n0b + 256; n0 += 32) {
        bf16x8 b[4], a[4];
#pragma unroll
        for (int cf = 0; cf < 4; ++cf)
            b[cf] = *(const bf16x8*)(Q + (size_t)(bcol + cf * 16 + l16) * N + n0 + lhi * 8);
#pragma unroll
        for (int ap = 0; ap < 4; ++ap)
            a[ap] = *(const bf16x8*)(P + (size_t)(arow + ap * 16 + l16) * N + n0 + lhi * 8);
#pragma unroll
        for (int ap = 0; ap < 4; ++ap)
#pragma unroll
            for (int cf = 0; cf < 4; ++cf)
                acc[ap][cf] = MFMA(a[ap], b[cf], acc[ap][cf]);
    }
    float* dst = part + ((size_t)blockIdx.z * 2 + blockIdx.y) * 65536;
#pragma unroll
    for (int ap = 0; ap < 4; ++ap)
#pragma unroll
        for (int cf = 0; cf < 4; ++cf)
#pragma unroll
            for (int jj = 0; jj < 4; ++jj)
                dst[(size_t)(arow + ap * 16 + lhi * 4 + jj) * D + bcol + cf * 16 + l16] = acc[ap][cf][jj];
}

// ---------------- sum 32 n-slices + cast to bf16 ----------------
__global__ __launch_bounds__(256) void k_cast(const float* __restrict__ part,
    u16* __restrict__ Mb, u16* __restrict__ XHT)
{
    int t = blockIdx.x * 256 + threadIdx.x;   // 0..131071
    int side = t >> 16, idx = t & 65535;
    float s = 0.f;
#pragma unroll
    for (int ks = 0; ks < 32; ++ks) s += part[((size_t)ks * 2 + side) * 65536 + idx];
    (side ? XHT : Mb)[idx] = f2bf(s);
}

// ---------------- dual 16-row GEMM (both rank-256 products in one launch) ----------------
__global__ __launch_bounds__(256, 4) void k_gemm16_dual(const u16* __restrict__ A,
    const u16* __restrict__ BT0, const u16* __restrict__ BT1,
    u16* __restrict__ out0, u16* __restrict__ out1)
{
    const u16* BT = blockIdx.y ? BT1 : BT0;
    u16* outb = blockIdx.y ? out1 : out0;
    int w = threadIdx.x >> 6;
    int lane = threadIdx.x & 63;
    int l16 = lane & 15, lhi = lane >> 4;
    int rows = blockIdx.x * 16;
    int cols = w * 64;
    const f32x4 z4 = {0.f, 0.f, 0.f, 0.f};
    f32x4 acc[4] = {z4, z4, z4, z4};
#pragma unroll
    for (int ks = 0; ks < 8; ++ks) {
        bf16x8 a = *(const bf16x8*)(A + (size_t)(rows + l16) * D + ks * 32 + lhi * 8);
#pragma unroll
        for (int cf = 0; cf < 4; ++cf) {
            bf16x8 b = *(const bf16x8*)(BT + (size_t)(cols + cf * 16 + l16) * D + ks * 32 + lhi * 8);
            acc[cf] = MFMA(a, b, acc[cf]);
        }
    }
#pragma unroll
    for (int cf = 0; cf < 4; ++cf)
#pragma unroll
        for (int jj = 0; jj < 4; ++jj)
            outb[(size_t)(rows + lhi * 4 + jj) * D + cols + cf * 16 + l16] = f2bf(acc[cf][jj]);
}

// ---------------- final GEMM: elu + residual, f32 out ----------------
__global__ __launch_bounds__(256, 4) void k_gemm16_elu(const u16* __restrict__ A,
    const u16* __restrict__ BT, const float* __restrict__ res, float* __restrict__ outf)
{
    int w = threadIdx.x >> 6;
    int lane = threadIdx.x & 63;
    int l16 = lane & 15, lhi = lane >> 4;
    int rows = blockIdx.x * 16;
    int cols = w * 64;
    const f32x4 z4 = {0.f, 0.f, 0.f, 0.f};
    f32x4 acc[4] = {z4, z4, z4, z4};
#pragma unroll
    for (int ks = 0; ks < 8; ++ks) {
        bf16x8 a = *(const bf16x8*)(A + (size_t)(rows + l16) * D + ks * 32 + lhi * 8);
#pragma unroll
        for (int cf = 0; cf < 4; ++cf) {
            bf16x8 b = *(const bf16x8*)(BT + (size_t)(cols + cf * 16 + l16) * D + ks * 32 + lhi * 8);
            acc[cf] = MFMA(a, b, acc[cf]);
        }
    }
#pragma unroll
    for (int cf = 0; cf < 4; ++cf)
#pragma unroll
        for (int jj = 0; jj < 4; ++jj) {
            int r = rows + lhi * 4 + jj;
            int c = cols + cf * 16 + l16;
            float v = acc[cf][jj];
            float z = v > 0.f ? v : expm1f(v);
            outf[(size_t)r * D + c] = z + res[(size_t)r * D + c];
        }
}

// ---------------- fused S pass v9 (banked best): XOR AK swizzle, 2 barriers/iter ----------------
__global__ __launch_bounds__(512, 4) void k_fused(const u16* __restrict__ kb,
    const u16* __restrict__ qb, const u16* __restrict__ hnT,
    const u16* __restrict__ xT, u16* __restrict__ accP, float* __restrict__ lpart)
{
    __shared__ u16 AK[64 * 256];      // 32KB: K rows, XOR slot swizzle (matches read pattern)
    __shared__ u16 P[64 * 256];       // 32KB: P tile (single buffer), XOR row swizzle
    const int tid = threadIdx.x;
    const int w = tid >> 6;
    const int lane = tid & 63;
    const int l16 = lane & 15, lhi = lane >> 4;
    const int wgid = blockIdx.x;
    const int xcd = wgid & 7;
    const int js = xcd >> 1;
    const int rb = ((wgid >> 3) << 1) | (xcd & 1);
    const int R0 = rb * 64;
    const int jbase = js * 2048;

    // ---- stage AK: physical slot = (s&16) | ((s&15) ^ (r&15)) ----
    {
        int r = tid >> 3, sb = (tid & 7) * 4;
        const u16* src = kb + (size_t)(R0 + r) * D + sb * 8;
#pragma unroll
        for (int i = 0; i < 4; ++i) {
            bf16x8 v = *(const bf16x8*)(src + i * 8);
            int s = sb + i;
            int slotp = (s & 16) | ((s & 15) ^ (r & 15));
            *(bf16x8*)(AK + r * 256 + slotp * 8) = v;
        }
    }
    __syncthreads();

    const int rg = w & 1;
    const int jf = w >> 1;
    const int t2 = w >> 2;
    const int ch = w & 3;
    const u16* T = t2 ? xT : hnT;
    const u16* Tb0 = T + (size_t)(ch * 64 + 0 * 16 + l16) * N + lhi * 8;
    const u16* Tb1 = T + (size_t)(ch * 64 + 1 * 16 + l16) * N + lhi * 8;
    const u16* Tb2 = T + (size_t)(ch * 64 + 2 * 16 + l16) * N + lhi * 8;
    const u16* Tb3 = T + (size_t)(ch * 64 + 3 * 16 + l16) * N + lhi * 8;

    const f32x4 z4 = {0.f, 0.f, 0.f, 0.f};
    f32x4 acc[16];
#pragma unroll
    for (int i = 0; i < 16; ++i) acc[i] = z4;
    f32x4 red2[2] = {z4, z4};
    bf16x8 tp0[4], tp1[4];

    for (int it = 0; it < 8; ++it) {
        const int jb = jbase + it * 256;
        asm volatile("s_waitcnt lgkmcnt(0)\n\ts_barrier" ::: "memory");

        // ---- phase 1: two 128-j subtiles; wave tile 32 rows x 32 j each ----
#pragma unroll
        for (int s = 0; s < 2; ++s) {
            const int jc = jb + s * 128 + jf * 32;
            f32x4 cs00 = z4, cs01 = z4, cs10 = z4, cs11 = z4;
#pragma unroll
            for (int ks = 0; ks < 8; ++ks) {
                int r0 = rg * 32 + l16;
                int r1 = r0 + 16;
                int sq = ks * 4 + lhi;
                int slx = (sq & 16) | ((sq & 15) ^ l16);
                bf16x8 a0 = *(const bf16x8*)(AK + r0 * 256 + slx * 8);
                bf16x8 a1 = *(const bf16x8*)(AK + r1 * 256 + slx * 8);
                const u16* Bq = qb + (size_t)(jc + l16) * D + ks * 32 + lhi * 8;
                bf16x8 b0 = *(const bf16x8*)(Bq);
                bf16x8 b1 = *(const bf16x8*)(Bq + 16 * D);
                cs00 = MFMA(a0, b0, cs00);
                cs01 = MFMA(a0, b1, cs01);
                cs10 = MFMA(a1, b0, cs10);
                cs11 = MFMA(a1, b1, cs11);
            }
#pragma unroll
            for (int rf = 0; rf < 2; ++rf)
#pragma unroll
                for (int cfr = 0; cfr < 2; ++cfr) {
                    f32x4 s4 = rf ? (cfr ? cs11 : cs10) : (cfr ? cs01 : cs00);
#pragma unroll
                    for (int jj = 0; jj < 4; ++jj) {
                        int row = rg * 32 + rf * 16 + lhi * 4 + jj;
                        int col = s * 128 + jf * 32 + cfr * 16 + l16;
                        float pv = __expf(s4[jj] * 0.0625f);
                        red2[rf][jj] += pv;
                        int slot = (col >> 3) ^ (row & 15);
                        *(u16*)((char*)P + row * 512 + slot * 16 + (col & 7) * 2) = f2bf(pv);
                    }
                }
        }
        // T prefetch for kf=0,1 — issued before barrier, stays in flight across it
        tp0[0] = *(const bf16x8*)(Tb0 + jb); tp0[1] = *(const bf16x8*)(Tb1 + jb);
        tp0[2] = *(const bf16x8*)(Tb2 + jb); tp0[3] = *(const bf16x8*)(Tb3 + jb);
        tp1[0] = *(const bf16x8*)(Tb0 + jb + 32); tp1[1] = *(const bf16x8*)(Tb1 + jb + 32);
        tp1[2] = *(const bf16x8*)(Tb2 + jb + 32); tp1[3] = *(const bf16x8*)(Tb3 + jb + 32);
        asm volatile("s_waitcnt lgkmcnt(0)\n\ts_barrier" ::: "memory");

        // ---- phase 2: 8 kf steps (K=32 each), rolling depth-2 T prefetch ----
        __builtin_amdgcn_s_setprio(1);
        const char* Pb = (const char*)P;
#define PV_STEP(KF, TP)                                                             \
        {                                                                           \
            bf16x8 pa0 = *(const bf16x8*)(Pb + (0 * 16 + l16) * 512 + ((((KF) * 4 + lhi) ^ l16) << 4)); \
            bf16x8 pa1 = *(const bf16x8*)(Pb + (1 * 16 + l16) * 512 + ((((KF) * 4 + lhi) ^ l16) << 4)); \
            bf16x8 pa2 = *(const bf16x8*)(Pb + (2 * 16 + l16) * 512 + ((((KF) * 4 + lhi) ^ l16) << 4)); \
            bf16x8 pa3 = *(const bf16x8*)(Pb + (3 * 16 + l16) * 512 + ((((KF) * 4 + lhi) ^ l16) << 4)); \
            acc[0]  = MFMA(pa0, TP[0], acc[0]);  acc[1]  = MFMA(pa0, TP[1], acc[1]);  \
            acc[2]  = MFMA(pa0, TP[2], acc[2]);  acc[3]  = MFMA(pa0, TP[3], acc[3]);  \
            acc[4]  = MFMA(pa1, TP[0], acc[4]);  acc[5]  = MFMA(pa1, TP[1], acc[5]);  \
            acc[6]  = MFMA(pa1, TP[2], acc[6]);  acc[7]  = MFMA(pa1, TP[3], acc[7]);  \
            acc[8]  = MFMA(pa2, TP[0], acc[8]);  acc[9]  = MFMA(pa2, TP[1], acc[9]);  \
            acc[10] = MFMA(pa2, TP[2], acc[10]); acc[11] = MFMA(pa2, TP[3], acc[11]); \
            acc[12] = MFMA(pa3, TP[0], acc[12]); acc[13] = MFMA(pa3, TP[1], acc[13]); \
            acc[14] = MFMA(pa3, TP[2], acc[14]); acc[15] = MFMA(pa3, TP[3], acc[15]); \
            if ((KF) + 2 < 8) {                                                     \
                TP[0] = *(const bf16x8*)(Tb0 + jb + ((KF) + 2) * 32);               \
                TP[1] = *(const bf16x8*)(Tb1 + jb + ((KF) + 2) * 32);               \
                TP[2] = *(const bf16x8*)(Tb2 + jb + ((KF) + 2) * 32);               \
                TP[3] = *(const bf16x8*)(Tb3 + jb + ((KF) + 2) * 32);               \
            }                                                                       \
        }
        PV_STEP(0, tp0)
        PV_STEP(1, tp1)
        PV_STEP(2, tp0)
        PV_STEP(3, tp1)
        PV_STEP(4, tp0)
        PV_STEP(5, tp1)
        PV_STEP(6, tp0)
        PV_STEP(7, tp1)
#undef PV_STEP
        __builtin_amdgcn_s_setprio(0);
    }

    // ---- coalesced nontemporal partial store: wave-private [64 v][64 lane] bf16 ----
    {
        u16* base = accP + ((((size_t)js * 128 + rb) * 8 + w) * 64) * 64 + lane;
#pragma unroll
        for (int rf = 0; rf < 4; ++rf)
#pragma unroll
            for (int cf = 0; cf < 4; ++cf)
#pragma unroll
                for (int jj = 0; jj < 4; ++jj) {
                    int v = (rf * 4 + cf) * 4 + jj;
                    __builtin_nontemporal_store(f2bf(acc[rf * 4 + cf][jj]), base + (size_t)v * 64);
                }
    }
    // ---- softmax denominator partials ----
#pragma unroll
    for (int rf = 0; rf < 2; ++rf)
#pragma unroll
        for (int m = 1; m < 16; m <<= 1) {
            red2[rf][0] += __shfl_xor(red2[rf][0], m);
            red2[rf][1] += __shfl_xor(red2[rf][1], m);
            red2[rf][2] += __shfl_xor(red2[rf][2], m);
            red2[rf][3] += __shfl_xor(red2[rf][3], m);
        }
    if (l16 == 0)
#pragma unroll
        for (int rf = 0; rf < 2; ++rf)
#pragma unroll
            for (int jj = 0; jj < 4; ++jj)
                atomicAdd(lpart + R0 + rg * 32 + rf * 16 + lhi * 4 + jj, red2[rf][jj]);
}

// ---------------- combine + inline stats: 2 rows/block; 128 threads per row ----------------
__global__ __launch_bounds__(256) void k_combine(const u16* __restrict__ accP,
    const float* __restrict__ lpart, const u16* __restrict__ Uh,
    const u16* __restrict__ Ux, const u16* __restrict__ xb,
    const float* __restrict__ mixing, const float* __restrict__ x0,
    u16* __restrict__ hmixb, float* __restrict__ outx)
{
    __shared__ float sred[2][2];
    int t = threadIdx.x;
    int rl = t >> 7;                       // row-local 0..1
    int q = t & 127;
    int r = blockIdx.x * 2 + rl;

    // ---- stats: sg = dot(Ux[r], xb[r]) via 128-thread reduce ----
    float sg;
    {
        int idx = q * 2;
        const u16* up = Ux + (size_t)r * D + idx;
        const u16* xp = xb + (size_t)r * D + idx;
        float part = bf2f(up[0]) * bf2f(xp[0]) + bf2f(up[1]) * bf2f(xp[1]);
#pragma unroll
        for (int m = 1; m < 64; m <<= 1) part += __shfl_xor(part, m);
        int wv = q >> 6;
        if ((t & 63) == 0) sred[rl][wv] = part;
        __syncthreads();
        sg = sred[rl][0] + sred[rl][1];
    }
    float inv_l = 1.0f / lpart[r];
    float inv_g = 1.0f / fmaxf(sqrtf(fmaxf(sg, 0.f)), 1e-12f);
    float e00 = __expf(mixing[0]), e10 = __expf(mixing[2]);
    float c00 = e00 / (e00 + e10), c10 = e10 / (e00 + e10);
    float e01 = __expf(mixing[1]), e11 = __expf(mixing[3]);
    float c01 = e01 / (e01 + e11), c11 = e11 / (e01 + e11);
    float stx = c00 * inv_l, sty = c10 * inv_g;
    float stz = c01 * inv_l, stw = c11 * inv_g;

    // ---- combine ----
    int rb = r >> 6, rr = r & 63;
    int t2 = q >> 6;
    int cc = (q & 63) * 4;
    int wv2 = t2 * 4 + (cc >> 6);
    int rf = rr >> 4, lhi = (rr >> 2) & 3, jj = rr & 3;
    int cf = (cc >> 4) & 3, l16 = cc & 15;
    int v = (rf * 4 + cf) * 4 + jj;
    int lane = lhi * 16 + l16;
    float v0 = 0.f, v1 = 0.f, v2 = 0.f, v3 = 0.f;
#pragma unroll
    for (int s = 0; s < 4; ++s) {
        const u16* bp = accP + ((((size_t)s * 128 + rb) * 8 + wv2) * 64 + v) * 64 + lane;
        ushort4 a = *(const ushort4*)bp;
        v0 += bf2f(a.x); v1 += bf2f(a.y); v2 += bf2f(a.z); v3 += bf2f(a.w);
    }
    if (t2 == 0) {
        int c = cc;
        ushort4 u = *(const ushort4*)(Uh + (size_t)r * D + c);
        ushort4 o;
        o.x = f2bf(stx * v0 + sty * bf2f(u.x));
        o.y = f2bf(stx * v1 + sty * bf2f(u.y));
        o.z = f2bf(stx * v2 + sty * bf2f(u.z));
        o.w = f2bf(stx * v3 + sty * bf2f(u.w));
        *(ushort4*)(hmixb + (size_t)r * D + c) = o;
    } else {
        int c = cc;
        ushort4 u = *(const ushort4*)(Ux + (size_t)r * D + c);
        float4 xv = *(const float4*)(x0 + (size_t)r * D + c);
        float4 o;
        o.x = stz * v0 + stw * bf2f(u.x) + xv.x;
        o.y = stz * v1 + stw * bf2f(u.y) + xv.y;
        o.z = stz * v2 + stw * bf2f(u.z) + xv.z;
        o.w = stz * v3 + stw * bf2f(u.w) + xv.w;
        *(float4*)(outx + (size_t)r * D + c) = o;
    }
}

extern "C" void kernel_launch(void* const* d_in, const int* in_sizes, int n_in,
                              void* d_out, int out_size, void* d_ws, size_t ws_size,
                              hipStream_t stream)
{
    const float* h = (const float*)d_in[0];
    const float* x = (const float*)d_in[1];
    const float* Wk = (const float*)d_in[2];
    const float* Wq = (const float*)d_in[3];
    const float* Wv = (const float*)d_in[4];
    const float* gamma = (const float*)d_in[5];
    const float* beta = (const float*)d_in[6];
    const float* mixing = (const float*)d_in[7];

    char* p = (char*)d_ws;
    const size_t ND2 = (size_t)N * D * 2;
    u16* hnb = (u16*)p; p += ND2;   // reused as Uh after k_trans_proj
    u16* xb = (u16*)p; p += ND2;
    u16* kb = (u16*)p; p += ND2;    // reused as hmixb after k_fused
    u16* qb = (u16*)p; p += ND2;
    u16* hnT = (u16*)p; p += ND2;
    u16* xT = (u16*)p; p += ND2;
    u16* Ux = (u16*)p; p += ND2;
    u16* wkT = (u16*)p; p += (size_t)D * D * 2;
    u16* wqT = (u16*)p; p += (size_t)D * D * 2;
    u16* wvT = (u16*)p; p += (size_t)D * D * 2;
    u16* Mb = (u16*)p; p += (size_t)D * D * 2;
    u16* XHT = (u16*)p; p += (size_t)D * D * 2;
    u16* accP = (u16*)p; p += (size_t)4 * N * 512 * 2;   // 32 MB bf16 wave-layout partials
    float* ntpart = (float*)accP;                        // overlay: 64 x 65536 f32 = 16MB, used before accP
    float* lpart = (float*)p; p += (size_t)N * 4;
    u16* Uh = hnb;      // overlay (hnb dead after k_trans_proj)
    u16* hmixb = kb;    // overlay (kb dead after k_fused)
    // total ~= 61 MB

    float* outh = (float*)d_out;
    float* outx = outh + (size_t)N * D;

    hipMemsetAsync(lpart, 0, (size_t)N * 4, stream);
    k_prep_all<<<2048 + 768, 256, 0, stream>>>(h, x, gamma, beta, hnb, xb,
                                               Wk, Wq, Wv, wkT, wqT, wvT);
    k_trans_proj<<<1024 + 512, 256, 0, stream>>>(hnb, hnT, xb, xT, wkT, wqT, kb, qb);
    k_small_nt<<<dim3(4, 2, 32), 256, 0, stream>>>(hnT, xT, ntpart);
    k_cast<<<512, 256, 0, stream>>>(ntpart, Mb, XHT);
    k_gemm16_dual<<<dim3(512, 2), 256, 0, stream>>>(xb, Mb, XHT, Ux, Uh);
    k_fused<<<512, 512, 0, stream>>>(kb, qb, hnT, xT, accP, lpart);
    k_combine<<<N / 2, 256, 0, stream>>>(accP, lpart, Uh, Ux, xb, mixing, x, hmixb, outx);
    k_gemm16_elu<<<512, 256, 0, stream>>>(hmixb, wvT, h, outh);
}